// Round 9
// baseline (754.218 us; speedup 1.0000x reference)
//
#include <hip/hip_runtime.h>
#include <hip/hip_bf16.h>

typedef short s16x8 __attribute__((ext_vector_type(8)));
typedef float f32x4 __attribute__((ext_vector_type(4)));
typedef float f32x2 __attribute__((ext_vector_type(2)));
typedef unsigned short us8 __attribute__((ext_vector_type(8)));
typedef unsigned short us4 __attribute__((ext_vector_type(4)));

#define T_TOK 8192
#define DDIM 1024
#define NEXP 8
#define FDIM 4096
#define MAXT 72
#define PADMAX (16384 + NEXP * 256)

#define GLOAD16(dst, src) \
  __builtin_amdgcn_global_load_lds((const __attribute__((address_space(1))) unsigned int*)(src), \
                                   (__attribute__((address_space(3))) unsigned int*)(dst), 16, 0, 0)
#define WAITVM(n) asm volatile("s_waitcnt vmcnt(" #n ")" ::: "memory")
#define MEMFENCE asm volatile("" ::: "memory")

// gelu(x) = x * sigmoid(x*(1.5957691 + 0.07135532 x^2)); exp+rcp form
__device__ __forceinline__ float gelu_fast(float x) {
  float x2 = x * x;
  float t = x * fmaf(x2, -0.07135532f, -1.5957691f);
  float e = __expf(t);
  return x * __builtin_amdgcn_rcpf(1.0f + e);
}
__device__ __forceinline__ float bf2f(unsigned short v) {
  return __uint_as_float((unsigned)v << 16);
}
__device__ __forceinline__ unsigned short f2bf(float f) {
  __hip_bfloat16 h = __float2bfloat16(f);
  return *(unsigned short*)&h;
}

// ---------------- gating ----------------
__global__ __launch_bounds__(256) void gate_kernel(
    const float* __restrict__ x, const float* __restrict__ gw,
    int* __restrict__ counts, int* __restrict__ tok_e, float* __restrict__ tok_w)
{
  int lane = threadIdx.x & 63;
  int tok = blockIdx.x * 4 + (threadIdx.x >> 6);
  const float* xr = x + (size_t)tok * DDIM;
  float acc[NEXP];
#pragma unroll
  for (int e = 0; e < NEXP; ++e) acc[e] = 0.f;
  for (int i = 0; i < DDIM / 64; ++i) {
    int d = i * 64 + lane;
    float xv = xr[d];
    const float* g = gw + (size_t)d * NEXP;
#pragma unroll
    for (int e = 0; e < NEXP; ++e) acc[e] += xv * g[e];
  }
#pragma unroll
  for (int off = 32; off > 0; off >>= 1) {
#pragma unroll
    for (int e = 0; e < NEXP; ++e) acc[e] += __shfl_xor(acc[e], off);
  }
  if (lane == 0) {
    int i1 = 0; float m1 = acc[0];
#pragma unroll
    for (int e = 1; e < NEXP; ++e) if (acc[e] > m1) { m1 = acc[e]; i1 = e; }
    int i2 = -1; float m2 = -3.4e38f;
#pragma unroll
    for (int e = 0; e < NEXP; ++e) if (e != i1 && acc[e] > m2) { m2 = acc[e]; i2 = e; }
    float w1 = 1.f / (1.f + expf(m2 - m1));
    tok_e[tok * 2] = i1; tok_e[tok * 2 + 1] = i2;
    tok_w[tok * 2] = w1; tok_w[tok * 2 + 1] = 1.f - w1;
    atomicAdd(&counts[i1], 1);
    atomicAdd(&counts[i2], 1);
  }
}

// ------- scan: pad to 256, tile table; also init pair_token to -1 -------
__global__ void scan_kernel(const int* __restrict__ counts, int* padded_off,
                            int* tile_e, int* tile_row, int* numTiles,
                            int* __restrict__ pair_token)
{
  if (blockIdx.x == 0) {
    for (int i = threadIdx.x; i < PADMAX; i += 256) pair_token[i] = -1;
    if (threadIdx.x == 0) {
      int off = 0, a = 0;
      for (int e = 0; e < NEXP; ++e) {
        padded_off[e] = off;
        int c = counts[e];
        int nt = (c + 255) / 256;
        for (int i = 0; i < nt; ++i) { tile_e[a] = e; tile_row[a] = off + i * 256; ++a; }
        off += nt * 256;
      }
      *numTiles = a;
    }
  }
}

__global__ void scatter_kernel(const int* __restrict__ tok_e,
                               const int* __restrict__ padded_off, int* __restrict__ fill,
                               int* __restrict__ pair_token, int* __restrict__ tok_slot)
{
  int tok = blockIdx.x * 256 + threadIdx.x;
  if (tok >= T_TOK) return;
#pragma unroll
  for (int k = 0; k < 2; ++k) {
    int e = tok_e[tok * 2 + k];
    int slot = padded_off[e] + atomicAdd(&fill[e], 1);
    pair_token[slot] = tok;
    tok_slot[tok * 2 + k] = slot;
  }
}

// ---------------- gather tokens -> bf16 rows (zeros for padding) ----------------
__global__ __launch_bounds__(256) void gather_x(
    const float* __restrict__ x, const int* __restrict__ pair_token,
    __hip_bfloat16* __restrict__ Xg)
{
  int gid = blockIdx.x * 256 + threadIdx.x;
  int r = gid >> 7;
  int c = (gid & 127) << 3;
  if (r >= PADMAX) return;
  int tk = pair_token[r];
  __hip_bfloat16 v[8];
  if (tk < 0) {
#pragma unroll
    for (int j = 0; j < 8; ++j) v[j] = __float2bfloat16(0.f);
  } else {
    const float* src = x + (size_t)tk * DDIM + c;
    f32x4 a = __builtin_nontemporal_load((const f32x4*)src);
    f32x4 b = __builtin_nontemporal_load((const f32x4*)(src + 4));
#pragma unroll
    for (int j = 0; j < 4; ++j) v[j] = __float2bfloat16(a[j]);
#pragma unroll
    for (int j = 0; j < 4; ++j) v[4 + j] = __float2bfloat16(b[j]);
  }
  *(us8*)(Xg + (size_t)r * DDIM + c) = *(const us8*)v;
}

// ------- fp32 (R,C) -> bf16 (C,R) transpose+convert, per expert z -------
// nt loads: the fp32 weights are read exactly once -> don't evict L3.
__global__ __launch_bounds__(256) void transpose_conv(
    const float* __restrict__ in, __hip_bfloat16* __restrict__ out, int R, int C)
{
  __shared__ __hip_bfloat16 tile[64][66];   // stride 33 dwords -> conflict-free
  size_t mat = (size_t)R * C;
  const float* ip = in + (size_t)blockIdx.z * mat;
  __hip_bfloat16* op = out + (size_t)blockIdx.z * mat;
  int c0 = blockIdx.x * 64, r0 = blockIdx.y * 64;
  int tx = threadIdx.x & 31, ty = threadIdx.x >> 5;
#pragma unroll
  for (int i = 0; i < 8; ++i) {
    int r = r0 + ty + i * 8;
    f32x2 v = __builtin_nontemporal_load(
        (const f32x2*)(ip + (size_t)r * C + c0 + tx * 2));
    tile[ty + i * 8][tx * 2]     = __float2bfloat16(v[0]);
    tile[ty + i * 8][tx * 2 + 1] = __float2bfloat16(v[1]);
  }
  __syncthreads();
#pragma unroll
  for (int i = 0; i < 8; ++i) {
    int cc = c0 + ty + i * 8;
    __hip_bfloat16 a = tile[tx * 2][ty + i * 8];
    __hip_bfloat16 b = tile[tx * 2 + 1][ty + i * 8];
    unsigned short ua = *(unsigned short*)&a, ub = *(unsigned short*)&b;
    unsigned int packed = (unsigned)ua | ((unsigned)ub << 16);
    *(unsigned int*)(op + (size_t)cc * R + r0 + tx * 2) = packed;
  }
}

// ---------------- 8-phase grouped GEMM, 256x256, BK=64 ----------------
// NTOUT: stream the output past the Infinity Cache (nt-store). Used for ffn1's
// 132 MB H stream so W1t/Xg panels stay L3-resident (the R7 FETCH=354MB thrash).
template<int LD, int NT, int LDO, int NCOL, int SC, bool GELU, bool NTOUT>
__global__ __launch_bounds__(512, 2) void moe_gemm8(
    const __hip_bfloat16* __restrict__ A, const __hip_bfloat16* __restrict__ B,
    __hip_bfloat16* __restrict__ Out,
    const int* __restrict__ tile_e, const int* __restrict__ tile_row,
    const int* __restrict__ numTiles)
{
  constexpr int TPX = MAXT / 8;          // 9 tiles per xcd
  constexpr int STU = 3 * SC;            // units per supertile
  constexpr int NCG = NCOL / SC;         // col groups
  const int bid = blockIdx.x;
  const int xcd = bid & 7;
  const int idx = bid >> 3;              // [0, TPX*NCOL)
  const int stg = idx / STU;
  const int within = idx % STU;
  const int colg = stg % NCG;
  const int tg = stg / NCG;
  const int tl = tg * 3 + within % 3;    // [0, TPX)
  const int col = colg * SC + within / 3;
  const int tile = tl * 8 + xcd;
  if (tile >= *numTiles) return;

  __shared__ __align__(16) __hip_bfloat16 lds[8][8192];
  const int t = threadIdx.x, lane = t & 63, w = t >> 6;
  const int wm = w >> 2, wn = w & 3;
  const int fr = lane & 15, fkg = lane >> 4;
  const size_t rowoff = (size_t)(w * 8 + (lane >> 3)) * LD + (((lane & 7) ^ (lane >> 3)) << 3);
  const int aoff = (wm * 64 + fr) * 64;
  const int boff = (wn * 32 + fr) * 64;
  const int swk0 = (fkg ^ (fr & 7)) * 8;
  const int swk1 = ((4 + fkg) ^ (fr & 7)) * 8;

  const int e = tile_e[tile];
  const int row0 = tile_row[tile];
  const int col0 = col * 256;
  const __hip_bfloat16* Ab = A + (size_t)row0 * LD;
  const __hip_bfloat16* Bb = B + (size_t)e * ((size_t)FDIM * DDIM) + (size_t)col0 * LD;

  auto STAGEH = [&](const __hip_bfloat16* base, int mat, int half, int tt) {
    __hip_bfloat16* d = &lds[(((tt & 1) << 2) | (mat << 1) | half)][0] + w * 512;
    const __hip_bfloat16* s = base + (size_t)(half * 128) * LD + (size_t)tt * 64 + rowoff;
    GLOAD16(d, s);
    GLOAD16(d + 4096, s + (size_t)64 * LD);
  };

  f32x4 acc[4][4][2] = {};
  // prologue: tile 0 halves in need-order A0, B0, B1, A1
  STAGEH(Ab, 0, 0, 0); STAGEH(Bb, 1, 0, 0); STAGEH(Bb, 1, 1, 0); STAGEH(Ab, 0, 1, 0);

  for (int kt = 0; kt < NT; ++kt) {
    const int buf = kt & 1;
    const bool pre = (kt + 1) < NT;
    const __hip_bfloat16* A0r = &lds[(buf << 2) | 0][0];
    const __hip_bfloat16* A1r = &lds[(buf << 2) | 1][0];
    const __hip_bfloat16* B0r = &lds[(buf << 2) | 2][0];
    const __hip_bfloat16* B1r = &lds[(buf << 2) | 3][0];
    s16x8 af[4][2], b0[2][2], b1[2][2];

    // ---- phase 1: quadrant (0,0) ----
    if (pre) STAGEH(Ab, 0, 0, kt + 1);
    if (pre) { WAITVM(6); } else { WAITVM(0); }
    __builtin_amdgcn_s_barrier();
    MEMFENCE;
#pragma unroll
    for (int m = 0; m < 4; ++m) {
      af[m][0] = *(const s16x8*)(A0r + aoff + m * 1024 + swk0);
      af[m][1] = *(const s16x8*)(A0r + aoff + m * 1024 + swk1);
    }
#pragma unroll
    for (int n = 0; n < 2; ++n) {
      b0[n][0] = *(const s16x8*)(B0r + boff + n * 1024 + swk0);
      b0[n][1] = *(const s16x8*)(B0r + boff + n * 1024 + swk1);
    }
    __builtin_amdgcn_s_setprio(1);
#pragma unroll
    for (int kk = 0; kk < 2; ++kk)
#pragma unroll
      for (int m = 0; m < 4; ++m)
#pragma unroll
        for (int n = 0; n < 2; ++n)
          acc[0][m][n] = __builtin_amdgcn_mfma_f32_16x16x32_bf16(af[m][kk], b0[n][kk], acc[0][m][n], 0, 0, 0);
    __builtin_amdgcn_s_setprio(0);
    MEMFENCE;

    // ---- phase 2: quadrant (0,1) ----
    if (pre) STAGEH(Bb, 1, 0, kt + 1);
    if (pre) { WAITVM(6); }
    __builtin_amdgcn_s_barrier();
    MEMFENCE;
#pragma unroll
    for (int n = 0; n < 2; ++n) {
      b1[n][0] = *(const s16x8*)(B1r + boff + n * 1024 + swk0);
      b1[n][1] = *(const s16x8*)(B1r + boff + n * 1024 + swk1);
    }
    __builtin_amdgcn_s_setprio(1);
#pragma unroll
    for (int kk = 0; kk < 2; ++kk)
#pragma unroll
      for (int m = 0; m < 4; ++m)
#pragma unroll
        for (int n = 0; n < 2; ++n)
          acc[1][m][n] = __builtin_amdgcn_mfma_f32_16x16x32_bf16(af[m][kk], b1[n][kk], acc[1][m][n], 0, 0, 0);
    __builtin_amdgcn_s_setprio(0);
    MEMFENCE;

    // ---- phase 3: quadrant (1,1) ----
    if (pre) STAGEH(Bb, 1, 1, kt + 1);
    if (pre) { WAITVM(6); }
    __builtin_amdgcn_s_barrier();
    MEMFENCE;
#pragma unroll
    for (int m = 0; m < 4; ++m) {
      af[m][0] = *(const s16x8*)(A1r + aoff + m * 1024 + swk0);
      af[m][1] = *(const s16x8*)(A1r + aoff + m * 1024 + swk1);
    }
    __builtin_amdgcn_s_setprio(1);
#pragma unroll
    for (int kk = 0; kk < 2; ++kk)
#pragma unroll
      for (int m = 0; m < 4; ++m)
#pragma unroll
        for (int n = 0; n < 2; ++n)
          acc[2][m][n] = __builtin_amdgcn_mfma_f32_16x16x32_bf16(af[m][kk], b1[n][kk], acc[2][m][n], 0, 0, 0);
    __builtin_amdgcn_s_setprio(0);
    MEMFENCE;

    // ---- phase 4: quadrant (1,0) ----
    if (pre) STAGEH(Ab, 0, 1, kt + 1);
    __builtin_amdgcn_s_barrier();
    MEMFENCE;
    __builtin_amdgcn_s_setprio(1);
#pragma unroll
    for (int kk = 0; kk < 2; ++kk)
#pragma unroll
      for (int m = 0; m < 4; ++m)
#pragma unroll
        for (int n = 0; n < 2; ++n)
          acc[3][m][n] = __builtin_amdgcn_mfma_f32_16x16x32_bf16(af[m][kk], b0[n][kk], acc[3][m][n], 0, 0, 0);
    __builtin_amdgcn_s_setprio(0);
    MEMFENCE;
  }

  // ---- epilogue: row-major, 4 imm-offset stores per row ----
  const int cbase = col0 + wn * 32 + fr;
#pragma unroll
  for (int mh = 0; mh < 2; ++mh) {
    const int qa = mh ? 3 : 0;   // qnh = 0
    const int qb = mh ? 2 : 1;   // qnh = 1
#pragma unroll
    for (int m = 0; m < 4; ++m) {
#pragma unroll
      for (int j = 0; j < 4; ++j) {
        int r = row0 + mh * 128 + wm * 64 + m * 16 + fkg * 4 + j;
        __hip_bfloat16* p = Out + (size_t)r * LDO + cbase;
        float v0 = acc[qa][m][0][j];
        float v1 = acc[qa][m][1][j];
        float v2 = acc[qb][m][0][j];
        float v3 = acc[qb][m][1][j];
        if (GELU) {
          v0 = gelu_fast(v0); v1 = gelu_fast(v1);
          v2 = gelu_fast(v2); v3 = gelu_fast(v3);
        }
        if (NTOUT) {
          __builtin_nontemporal_store(f2bf(v0), (unsigned short*)(p + 0));
          __builtin_nontemporal_store(f2bf(v1), (unsigned short*)(p + 16));
          __builtin_nontemporal_store(f2bf(v2), (unsigned short*)(p + 128));
          __builtin_nontemporal_store(f2bf(v3), (unsigned short*)(p + 144));
        } else {
          p[0]   = __float2bfloat16(v0);
          p[16]  = __float2bfloat16(v1);
          p[128] = __float2bfloat16(v2);
          p[144] = __float2bfloat16(v3);
        }
      }
    }
  }
}

// ---------------- combine: out[tok] = wa*Eout[sa] + wb*Eout[sb] ----------------
__global__ __launch_bounds__(256) void combine_kernel(
    const __hip_bfloat16* __restrict__ Eout, const int* __restrict__ tok_slot,
    const float* __restrict__ tok_w, float* __restrict__ out)
{
  int tok = blockIdx.x;
  int sa = tok_slot[tok * 2], sb = tok_slot[tok * 2 + 1];
  float wa = tok_w[tok * 2], wb = tok_w[tok * 2 + 1];
  const __hip_bfloat16* ra = Eout + (size_t)sa * DDIM;
  const __hip_bfloat16* rb = Eout + (size_t)sb * DDIM;
  float* op = out + (size_t)tok * DDIM;
  int c = threadIdx.x * 4;
  us4 va = *(const us4*)(ra + c);
  us4 vb = *(const us4*)(rb + c);
  float4 o;
  o.x = wa * bf2f(va.x) + wb * bf2f(vb.x);
  o.y = wa * bf2f(va.y) + wb * bf2f(vb.y);
  o.z = wa * bf2f(va.z) + wb * bf2f(vb.z);
  o.w = wa * bf2f(va.w) + wb * bf2f(vb.w);
  *(float4*)(op + c) = o;
}

extern "C" void kernel_launch(void* const* d_in, const int* in_sizes, int n_in,
                              void* d_out, int out_size, void* d_ws, size_t ws_size,
                              hipStream_t stream)
{
  const float* x      = (const float*)d_in[0];
  const float* gate_w = (const float*)d_in[1];
  const float* w1     = (const float*)d_in[2];
  const float* w2     = (const float*)d_in[3];
  float* out = (float*)d_out;

  char* ws = (char*)d_ws;
  size_t off = 0;
  auto alloc = [&](size_t bytes) -> void* {
    void* p = ws + off;
    off = (off + bytes + 255) & ~(size_t)255;
    return p;
  };
  int* ctrl = (int*)alloc(1024);          // zeroed control block
  int* counts     = ctrl + 0;
  int* fill       = ctrl + 8;
  int* padded_off = ctrl + 16;
  int* numTiles   = ctrl + 24;
  int*   tile_e     = (int*)alloc(MAXT * 4);
  int*   tile_row   = (int*)alloc(MAXT * 4);
  int*   tok_e      = (int*)alloc((size_t)T_TOK * 2 * 4);
  float* tok_w      = (float*)alloc((size_t)T_TOK * 2 * 4);
  int*   tok_slot   = (int*)alloc((size_t)T_TOK * 2 * 4);
  int*   pair_token = (int*)alloc((size_t)PADMAX * 4);
  __hip_bfloat16* XgEout = (__hip_bfloat16*)alloc((size_t)PADMAX * DDIM * 2); // Xg, later Eout
  __hip_bfloat16* W1t  = (__hip_bfloat16*)alloc((size_t)NEXP * FDIM * DDIM * 2);
  __hip_bfloat16* W2t  = (__hip_bfloat16*)alloc((size_t)NEXP * FDIM * DDIM * 2);
  __hip_bfloat16* Hbuf = (__hip_bfloat16*)alloc((size_t)PADMAX * FDIM * 2);
  (void)in_sizes; (void)n_in; (void)ws_size; (void)out_size;

  (void)hipMemsetAsync(d_ws, 0, 1024, stream);

  gate_kernel<<<T_TOK / 4, 256, 0, stream>>>(x, gate_w, counts, tok_e, tok_w);
  scan_kernel<<<1, 256, 0, stream>>>(counts, padded_off, tile_e, tile_row, numTiles,
                                     pair_token);
  scatter_kernel<<<T_TOK / 256, 256, 0, stream>>>(tok_e, padded_off, fill,
                                                  pair_token, tok_slot);
  gather_x<<<(PADMAX * (DDIM / 8) + 255) / 256, 256, 0, stream>>>(x, pair_token, XgEout);

  transpose_conv<<<dim3(FDIM / 64, DDIM / 64, NEXP), 256, 0, stream>>>(w1, W1t, DDIM, FDIM);

  // ffn1: H = gelu(Xg @ W1t[e]^T); nt-store H so W1t/Xg stay L3-resident
  moe_gemm8<DDIM, DDIM / 64, FDIM, FDIM / 256, 8, true, true>
      <<<MAXT * (FDIM / 256), 512, 0, stream>>>(XgEout, W1t, Hbuf,
                                                tile_e, tile_row, numTiles);

  transpose_conv<<<dim3(DDIM / 64, FDIM / 64, NEXP), 256, 0, stream>>>(w2, W2t, FDIM, DDIM);

  // ffn2: Eout = H @ W2t[e]^T (normal stores; Eout is read right after)
  moe_gemm8<FDIM, FDIM / 64, DDIM, DDIM / 256, 4, false, false>
      <<<MAXT * (DDIM / 256), 512, 0, stream>>>(Hbuf, W2t, XgEout,
                                                tile_e, tile_row, numTiles);

  combine_kernel<<<T_TOK, 256, 0, stream>>>(XgEout, tok_slot, tok_w, out);
}

// Round 10
// 743.267 us; speedup vs baseline: 1.0147x; 1.0147x over previous
//
#include <hip/hip_runtime.h>
#include <hip/hip_bf16.h>

typedef short s16x8 __attribute__((ext_vector_type(8)));
typedef float f32x4 __attribute__((ext_vector_type(4)));
typedef float f32x2 __attribute__((ext_vector_type(2)));
typedef unsigned short us8 __attribute__((ext_vector_type(8)));
typedef unsigned short us4 __attribute__((ext_vector_type(4)));

#define T_TOK 8192
#define DDIM 1024
#define NEXP 8
#define FDIM 4096
#define MAXT 72
#define PADMAX (16384 + NEXP * 256)

#define GLOAD16(dst, src) \
  __builtin_amdgcn_global_load_lds((const __attribute__((address_space(1))) unsigned int*)(src), \
                                   (__attribute__((address_space(3))) unsigned int*)(dst), 16, 0, 0)
#define WAITVM(n) asm volatile("s_waitcnt vmcnt(" #n ")" ::: "memory")
#define MEMFENCE asm volatile("" ::: "memory")

// gelu(x) = x * sigmoid(x*(1.5957691 + 0.07135532 x^2)); exp+rcp form
__device__ __forceinline__ float gelu_fast(float x) {
  float x2 = x * x;
  float t = x * fmaf(x2, -0.07135532f, -1.5957691f);
  float e = __expf(t);
  return x * __builtin_amdgcn_rcpf(1.0f + e);
}
__device__ __forceinline__ float bf2f(unsigned short v) {
  return __uint_as_float((unsigned)v << 16);
}

// ---------------- gating ----------------
__global__ __launch_bounds__(256) void gate_kernel(
    const float* __restrict__ x, const float* __restrict__ gw,
    int* __restrict__ counts, int* __restrict__ tok_e, float* __restrict__ tok_w)
{
  int lane = threadIdx.x & 63;
  int tok = blockIdx.x * 4 + (threadIdx.x >> 6);
  const float* xr = x + (size_t)tok * DDIM;
  float acc[NEXP];
#pragma unroll
  for (int e = 0; e < NEXP; ++e) acc[e] = 0.f;
  for (int i = 0; i < DDIM / 64; ++i) {
    int d = i * 64 + lane;
    float xv = xr[d];
    const float* g = gw + (size_t)d * NEXP;
#pragma unroll
    for (int e = 0; e < NEXP; ++e) acc[e] += xv * g[e];
  }
#pragma unroll
  for (int off = 32; off > 0; off >>= 1) {
#pragma unroll
    for (int e = 0; e < NEXP; ++e) acc[e] += __shfl_xor(acc[e], off);
  }
  if (lane == 0) {
    int i1 = 0; float m1 = acc[0];
#pragma unroll
    for (int e = 1; e < NEXP; ++e) if (acc[e] > m1) { m1 = acc[e]; i1 = e; }
    int i2 = -1; float m2 = -3.4e38f;
#pragma unroll
    for (int e = 0; e < NEXP; ++e) if (e != i1 && acc[e] > m2) { m2 = acc[e]; i2 = e; }
    float w1 = 1.f / (1.f + expf(m2 - m1));
    tok_e[tok * 2] = i1; tok_e[tok * 2 + 1] = i2;
    tok_w[tok * 2] = w1; tok_w[tok * 2 + 1] = 1.f - w1;
    atomicAdd(&counts[i1], 1);
    atomicAdd(&counts[i2], 1);
  }
}

// ------- scan: pad to 256, tile table; also init pair_token to -1 -------
__global__ void scan_kernel(const int* __restrict__ counts, int* padded_off,
                            int* tile_e, int* tile_row, int* numTiles,
                            int* __restrict__ pair_token)
{
  if (blockIdx.x == 0) {
    for (int i = threadIdx.x; i < PADMAX; i += 256) pair_token[i] = -1;
    if (threadIdx.x == 0) {
      int off = 0, a = 0;
      for (int e = 0; e < NEXP; ++e) {
        padded_off[e] = off;
        int c = counts[e];
        int nt = (c + 255) / 256;
        for (int i = 0; i < nt; ++i) { tile_e[a] = e; tile_row[a] = off + i * 256; ++a; }
        off += nt * 256;
      }
      *numTiles = a;
    }
  }
}

__global__ void scatter_kernel(const int* __restrict__ tok_e,
                               const int* __restrict__ padded_off, int* __restrict__ fill,
                               int* __restrict__ pair_token, int* __restrict__ tok_slot)
{
  int tok = blockIdx.x * 256 + threadIdx.x;
  if (tok >= T_TOK) return;
#pragma unroll
  for (int k = 0; k < 2; ++k) {
    int e = tok_e[tok * 2 + k];
    int slot = padded_off[e] + atomicAdd(&fill[e], 1);
    pair_token[slot] = tok;
    tok_slot[tok * 2 + k] = slot;
  }
}

// ---------------- gather tokens -> bf16 rows (zeros for padding) ----------------
__global__ __launch_bounds__(256) void gather_x(
    const float* __restrict__ x, const int* __restrict__ pair_token,
    __hip_bfloat16* __restrict__ Xg)
{
  int gid = blockIdx.x * 256 + threadIdx.x;
  int r = gid >> 7;
  int c = (gid & 127) << 3;
  if (r >= PADMAX) return;
  int tk = pair_token[r];
  __hip_bfloat16 v[8];
  if (tk < 0) {
#pragma unroll
    for (int j = 0; j < 8; ++j) v[j] = __float2bfloat16(0.f);
  } else {
    const float* src = x + (size_t)tk * DDIM + c;
    f32x4 a = __builtin_nontemporal_load((const f32x4*)src);
    f32x4 b = __builtin_nontemporal_load((const f32x4*)(src + 4));
#pragma unroll
    for (int j = 0; j < 4; ++j) v[j] = __float2bfloat16(a[j]);
#pragma unroll
    for (int j = 0; j < 4; ++j) v[4 + j] = __float2bfloat16(b[j]);
  }
  *(us8*)(Xg + (size_t)r * DDIM + c) = *(const us8*)v;
}

// ------- fp32 (R,C) -> bf16 (C,R) transpose+convert, per expert z -------
__global__ __launch_bounds__(256) void transpose_conv(
    const float* __restrict__ in, __hip_bfloat16* __restrict__ out, int R, int C)
{
  __shared__ __hip_bfloat16 tile[64][66];   // stride 33 dwords -> conflict-free
  size_t mat = (size_t)R * C;
  const float* ip = in + (size_t)blockIdx.z * mat;
  __hip_bfloat16* op = out + (size_t)blockIdx.z * mat;
  int c0 = blockIdx.x * 64, r0 = blockIdx.y * 64;
  int tx = threadIdx.x & 31, ty = threadIdx.x >> 5;
#pragma unroll
  for (int i = 0; i < 8; ++i) {
    int r = r0 + ty + i * 8;
    f32x2 v = __builtin_nontemporal_load(
        (const f32x2*)(ip + (size_t)r * C + c0 + tx * 2));
    tile[ty + i * 8][tx * 2]     = __float2bfloat16(v[0]);
    tile[ty + i * 8][tx * 2 + 1] = __float2bfloat16(v[1]);
  }
  __syncthreads();
#pragma unroll
  for (int i = 0; i < 8; ++i) {
    int cc = c0 + ty + i * 8;
    __hip_bfloat16 a = tile[tx * 2][ty + i * 8];
    __hip_bfloat16 b = tile[tx * 2 + 1][ty + i * 8];
    unsigned short ua = *(unsigned short*)&a, ub = *(unsigned short*)&b;
    unsigned int packed = (unsigned)ua | ((unsigned)ub << 16);
    *(unsigned int*)(op + (size_t)cc * R + r0 + tx * 2) = packed;
  }
}

// ---------------- 8-phase grouped GEMM, 256x256, BK=64 ----------------
// XCD mapping: each XCD owns a CONTIGUOUS, runtime-balanced tile range
// [xcd*nT/8, (xcd+1)*nT/8) so its 8-9 tiles span ~1 expert -> B-panels are
// L2-filterable (R8: interleaved mapping gave 353MB L2-miss vs 97MB unique).
template<int LD, int NT, int LDO, int NCOL, int SC, bool GELU>
__global__ __launch_bounds__(512, 2) void moe_gemm8(
    const __hip_bfloat16* __restrict__ A, const __hip_bfloat16* __restrict__ B,
    __hip_bfloat16* __restrict__ Out,
    const int* __restrict__ tile_e, const int* __restrict__ tile_row,
    const int* __restrict__ numTiles)
{
  constexpr int STU = 3 * SC;            // units per supertile
  constexpr int NCG = NCOL / SC;         // col groups
  const int bid = blockIdx.x;
  const int xcd = bid & 7;
  const int idx = bid >> 3;              // [0, TPX*NCOL)
  const int stg = idx / STU;
  const int within = idx % STU;
  const int colg = stg % NCG;
  const int tg = stg / NCG;
  const int tl = tg * 3 + within % 3;    // [0, 9)
  const int col = colg * SC + within / 3;
  const int nT = *numTiles;
  const int tile = ((xcd * nT) >> 3) + tl;
  if (tile >= (((xcd + 1) * nT) >> 3)) return;

  __shared__ __align__(16) __hip_bfloat16 lds[8][8192];
  const int t = threadIdx.x, lane = t & 63, w = t >> 6;
  const int wm = w >> 2, wn = w & 3;
  const int fr = lane & 15, fkg = lane >> 4;
  const size_t rowoff = (size_t)(w * 8 + (lane >> 3)) * LD + (((lane & 7) ^ (lane >> 3)) << 3);
  const int aoff = (wm * 64 + fr) * 64;
  const int boff = (wn * 32 + fr) * 64;
  const int swk0 = (fkg ^ (fr & 7)) * 8;
  const int swk1 = ((4 + fkg) ^ (fr & 7)) * 8;

  const int e = tile_e[tile];
  const int row0 = tile_row[tile];
  const int col0 = col * 256;
  const __hip_bfloat16* Ab = A + (size_t)row0 * LD;
  const __hip_bfloat16* Bb = B + (size_t)e * ((size_t)FDIM * DDIM) + (size_t)col0 * LD;

  auto STAGEH = [&](const __hip_bfloat16* base, int mat, int half, int tt) {
    __hip_bfloat16* d = &lds[(((tt & 1) << 2) | (mat << 1) | half)][0] + w * 512;
    const __hip_bfloat16* s = base + (size_t)(half * 128) * LD + (size_t)tt * 64 + rowoff;
    GLOAD16(d, s);
    GLOAD16(d + 4096, s + (size_t)64 * LD);
  };

  f32x4 acc[4][4][2] = {};
  // prologue: tile 0 halves in need-order A0, B0, B1, A1
  STAGEH(Ab, 0, 0, 0); STAGEH(Bb, 1, 0, 0); STAGEH(Bb, 1, 1, 0); STAGEH(Ab, 0, 1, 0);

  for (int kt = 0; kt < NT; ++kt) {
    const int buf = kt & 1;
    const bool pre = (kt + 1) < NT;
    const __hip_bfloat16* A0r = &lds[(buf << 2) | 0][0];
    const __hip_bfloat16* A1r = &lds[(buf << 2) | 1][0];
    const __hip_bfloat16* B0r = &lds[(buf << 2) | 2][0];
    const __hip_bfloat16* B1r = &lds[(buf << 2) | 3][0];
    s16x8 af[4][2], b0[2][2], b1[2][2];

    // ---- phase 1: quadrant (0,0) ----
    if (pre) STAGEH(Ab, 0, 0, kt + 1);
    if (pre) { WAITVM(6); } else { WAITVM(0); }
    __builtin_amdgcn_s_barrier();
    MEMFENCE;
#pragma unroll
    for (int m = 0; m < 4; ++m) {
      af[m][0] = *(const s16x8*)(A0r + aoff + m * 1024 + swk0);
      af[m][1] = *(const s16x8*)(A0r + aoff + m * 1024 + swk1);
    }
#pragma unroll
    for (int n = 0; n < 2; ++n) {
      b0[n][0] = *(const s16x8*)(B0r + boff + n * 1024 + swk0);
      b0[n][1] = *(const s16x8*)(B0r + boff + n * 1024 + swk1);
    }
    __builtin_amdgcn_s_setprio(1);
#pragma unroll
    for (int kk = 0; kk < 2; ++kk)
#pragma unroll
      for (int m = 0; m < 4; ++m)
#pragma unroll
        for (int n = 0; n < 2; ++n)
          acc[0][m][n] = __builtin_amdgcn_mfma_f32_16x16x32_bf16(af[m][kk], b0[n][kk], acc[0][m][n], 0, 0, 0);
    __builtin_amdgcn_s_setprio(0);
    MEMFENCE;

    // ---- phase 2: quadrant (0,1) ----
    if (pre) STAGEH(Bb, 1, 0, kt + 1);
    if (pre) { WAITVM(6); }
    __builtin_amdgcn_s_barrier();
    MEMFENCE;
#pragma unroll
    for (int n = 0; n < 2; ++n) {
      b1[n][0] = *(const s16x8*)(B1r + boff + n * 1024 + swk0);
      b1[n][1] = *(const s16x8*)(B1r + boff + n * 1024 + swk1);
    }
    __builtin_amdgcn_s_setprio(1);
#pragma unroll
    for (int kk = 0; kk < 2; ++kk)
#pragma unroll
      for (int m = 0; m < 4; ++m)
#pragma unroll
        for (int n = 0; n < 2; ++n)
          acc[1][m][n] = __builtin_amdgcn_mfma_f32_16x16x32_bf16(af[m][kk], b1[n][kk], acc[1][m][n], 0, 0, 0);
    __builtin_amdgcn_s_setprio(0);
    MEMFENCE;

    // ---- phase 3: quadrant (1,1) ----
    if (pre) STAGEH(Bb, 1, 1, kt + 1);
    if (pre) { WAITVM(6); }
    __builtin_amdgcn_s_barrier();
    MEMFENCE;
#pragma unroll
    for (int m = 0; m < 4; ++m) {
      af[m][0] = *(const s16x8*)(A1r + aoff + m * 1024 + swk0);
      af[m][1] = *(const s16x8*)(A1r + aoff + m * 1024 + swk1);
    }
    __builtin_amdgcn_s_setprio(1);
#pragma unroll
    for (int kk = 0; kk < 2; ++kk)
#pragma unroll
      for (int m = 0; m < 4; ++m)
#pragma unroll
        for (int n = 0; n < 2; ++n)
          acc[2][m][n] = __builtin_amdgcn_mfma_f32_16x16x32_bf16(af[m][kk], b1[n][kk], acc[2][m][n], 0, 0, 0);
    __builtin_amdgcn_s_setprio(0);
    MEMFENCE;

    // ---- phase 4: quadrant (1,0) ----
    if (pre) STAGEH(Ab, 0, 1, kt + 1);
    __builtin_amdgcn_s_barrier();
    MEMFENCE;
    __builtin_amdgcn_s_setprio(1);
#pragma unroll
    for (int kk = 0; kk < 2; ++kk)
#pragma unroll
      for (int m = 0; m < 4; ++m)
#pragma unroll
        for (int n = 0; n < 2; ++n)
          acc[3][m][n] = __builtin_amdgcn_mfma_f32_16x16x32_bf16(af[m][kk], b0[n][kk], acc[3][m][n], 0, 0, 0);
    __builtin_amdgcn_s_setprio(0);
    MEMFENCE;
  }

  // ---- epilogue: row-major, 4 imm-offset stores per row ----
  const int cbase = col0 + wn * 32 + fr;
#pragma unroll
  for (int mh = 0; mh < 2; ++mh) {
    const int qa = mh ? 3 : 0;   // qnh = 0
    const int qb = mh ? 2 : 1;   // qnh = 1
#pragma unroll
    for (int m = 0; m < 4; ++m) {
#pragma unroll
      for (int j = 0; j < 4; ++j) {
        int r = row0 + mh * 128 + wm * 64 + m * 16 + fkg * 4 + j;
        __hip_bfloat16* p = Out + (size_t)r * LDO + cbase;
        float v0 = acc[qa][m][0][j];
        float v1 = acc[qa][m][1][j];
        float v2 = acc[qb][m][0][j];
        float v3 = acc[qb][m][1][j];
        if (GELU) {
          v0 = gelu_fast(v0); v1 = gelu_fast(v1);
          v2 = gelu_fast(v2); v3 = gelu_fast(v3);
        }
        p[0]   = __float2bfloat16(v0);
        p[16]  = __float2bfloat16(v1);
        p[128] = __float2bfloat16(v2);
        p[144] = __float2bfloat16(v3);
      }
    }
  }
}

// ---------------- combine: out[tok] = wa*Eout[sa] + wb*Eout[sb] ----------------
__global__ __launch_bounds__(256) void combine_kernel(
    const __hip_bfloat16* __restrict__ Eout, const int* __restrict__ tok_slot,
    const float* __restrict__ tok_w, float* __restrict__ out)
{
  int tok = blockIdx.x;
  int sa = tok_slot[tok * 2], sb = tok_slot[tok * 2 + 1];
  float wa = tok_w[tok * 2], wb = tok_w[tok * 2 + 1];
  const __hip_bfloat16* ra = Eout + (size_t)sa * DDIM;
  const __hip_bfloat16* rb = Eout + (size_t)sb * DDIM;
  float* op = out + (size_t)tok * DDIM;
  int c = threadIdx.x * 4;
  us4 va = *(const us4*)(ra + c);
  us4 vb = *(const us4*)(rb + c);
  float4 o;
  o.x = wa * bf2f(va.x) + wb * bf2f(vb.x);
  o.y = wa * bf2f(va.y) + wb * bf2f(vb.y);
  o.z = wa * bf2f(va.z) + wb * bf2f(vb.z);
  o.w = wa * bf2f(va.w) + wb * bf2f(vb.w);
  *(float4*)(op + c) = o;
}

extern "C" void kernel_launch(void* const* d_in, const int* in_sizes, int n_in,
                              void* d_out, int out_size, void* d_ws, size_t ws_size,
                              hipStream_t stream)
{
  const float* x      = (const float*)d_in[0];
  const float* gate_w = (const float*)d_in[1];
  const float* w1     = (const float*)d_in[2];
  const float* w2     = (const float*)d_in[3];
  float* out = (float*)d_out;

  char* ws = (char*)d_ws;
  size_t off = 0;
  auto alloc = [&](size_t bytes) -> void* {
    void* p = ws + off;
    off = (off + bytes + 255) & ~(size_t)255;
    return p;
  };
  int* ctrl = (int*)alloc(1024);          // zeroed control block
  int* counts     = ctrl + 0;
  int* fill       = ctrl + 8;
  int* padded_off = ctrl + 16;
  int* numTiles   = ctrl + 24;
  int*   tile_e     = (int*)alloc(MAXT * 4);
  int*   tile_row   = (int*)alloc(MAXT * 4);
  int*   tok_e      = (int*)alloc((size_t)T_TOK * 2 * 4);
  float* tok_w      = (float*)alloc((size_t)T_TOK * 2 * 4);
  int*   tok_slot   = (int*)alloc((size_t)T_TOK * 2 * 4);
  int*   pair_token = (int*)alloc((size_t)PADMAX * 4);
  __hip_bfloat16* XgEout = (__hip_bfloat16*)alloc((size_t)PADMAX * DDIM * 2); // Xg, later Eout
  __hip_bfloat16* W1t  = (__hip_bfloat16*)alloc((size_t)NEXP * FDIM * DDIM * 2);
  __hip_bfloat16* W2t  = (__hip_bfloat16*)alloc((size_t)NEXP * FDIM * DDIM * 2);
  __hip_bfloat16* Hbuf = (__hip_bfloat16*)alloc((size_t)PADMAX * FDIM * 2);
  (void)in_sizes; (void)n_in; (void)ws_size; (void)out_size;

  (void)hipMemsetAsync(d_ws, 0, 1024, stream);

  gate_kernel<<<T_TOK / 4, 256, 0, stream>>>(x, gate_w, counts, tok_e, tok_w);
  scan_kernel<<<1, 256, 0, stream>>>(counts, padded_off, tile_e, tile_row, numTiles,
                                     pair_token);
  scatter_kernel<<<T_TOK / 256, 256, 0, stream>>>(tok_e, padded_off, fill,
                                                  pair_token, tok_slot);
  gather_x<<<(PADMAX * (DDIM / 8) + 255) / 256, 256, 0, stream>>>(x, pair_token, XgEout);

  transpose_conv<<<dim3(FDIM / 64, DDIM / 64, NEXP), 256, 0, stream>>>(w1, W1t, DDIM, FDIM);

  // ffn1: H = gelu(Xg @ W1t[e]^T)   (K=1024, N=4096)
  moe_gemm8<DDIM, DDIM / 64, FDIM, FDIM / 256, 8, true>
      <<<MAXT * (FDIM / 256), 512, 0, stream>>>(XgEout, W1t, Hbuf,
                                                tile_e, tile_row, numTiles);

  transpose_conv<<<dim3(DDIM / 64, FDIM / 64, NEXP), 256, 0, stream>>>(w2, W2t, FDIM, DDIM);

  // ffn2: Eout = H @ W2t[e]^T       (K=4096, N=1024)
  moe_gemm8<FDIM, FDIM / 64, DDIM, DDIM / 256, 4, false>
      <<<MAXT * (DDIM / 256), 512, 0, stream>>>(Hbuf, W2t, XgEout,
                                                tile_e, tile_row, numTiles);

  combine_kernel<<<T_TOK, 256, 0, stream>>>(XgEout, tok_slot, tok_w, out);
}

// Round 11
// 485.762 us; speedup vs baseline: 1.5526x; 1.5301x over previous
//
#include <hip/hip_runtime.h>
#include <hip/hip_bf16.h>

typedef short s16x8 __attribute__((ext_vector_type(8)));
typedef float f32x4 __attribute__((ext_vector_type(4)));
typedef float f32x2 __attribute__((ext_vector_type(2)));
typedef unsigned short us8 __attribute__((ext_vector_type(8)));
typedef unsigned short us4 __attribute__((ext_vector_type(4)));

#define T_TOK 8192
#define DDIM 1024
#define NEXP 8
#define FDIM 4096
#define MAXT 72
#define PADMAX (16384 + NEXP * 256)

#define GLOAD16(dst, src) \
  __builtin_amdgcn_global_load_lds((const __attribute__((address_space(1))) unsigned int*)(src), \
                                   (__attribute__((address_space(3))) unsigned int*)(dst), 16, 0, 0)
#define WAITVM(n) asm volatile("s_waitcnt vmcnt(" #n ")" ::: "memory")
#define MEMFENCE asm volatile("" ::: "memory")

__device__ __forceinline__ float gelu_fast(float x) {
  float x2 = x * x;
  float t = x * fmaf(x2, -0.07135532f, -1.5957691f);
  float e = __expf(t);
  return x * __builtin_amdgcn_rcpf(1.0f + e);
}
__device__ __forceinline__ float bf2f(unsigned short v) {
  return __uint_as_float((unsigned)v << 16);
}

// ---------------- gating (no atomics; counts done by count_kernel) ----------------
__global__ __launch_bounds__(256) void gate_kernel(
    const float* __restrict__ x, const float* __restrict__ gw,
    int* __restrict__ tok_e, float* __restrict__ tok_w)
{
  int lane = threadIdx.x & 63;
  int tok = blockIdx.x * 4 + (threadIdx.x >> 6);
  const float* xr = x + (size_t)tok * DDIM;
  float acc[NEXP];
#pragma unroll
  for (int e = 0; e < NEXP; ++e) acc[e] = 0.f;
  for (int i = 0; i < DDIM / 64; ++i) {
    int d = i * 64 + lane;
    float xv = xr[d];
    const float* g = gw + (size_t)d * NEXP;
#pragma unroll
    for (int e = 0; e < NEXP; ++e) acc[e] += xv * g[e];
  }
#pragma unroll
  for (int off = 32; off > 0; off >>= 1) {
#pragma unroll
    for (int e = 0; e < NEXP; ++e) acc[e] += __shfl_xor(acc[e], off);
  }
  if (lane == 0) {
    int i1 = 0; float m1 = acc[0];
#pragma unroll
    for (int e = 1; e < NEXP; ++e) if (acc[e] > m1) { m1 = acc[e]; i1 = e; }
    int i2 = -1; float m2 = -3.4e38f;
#pragma unroll
    for (int e = 0; e < NEXP; ++e) if (e != i1 && acc[e] > m2) { m2 = acc[e]; i2 = e; }
    float w1 = 1.f / (1.f + expf(m2 - m1));
    tok_e[tok * 2] = i1; tok_e[tok * 2 + 1] = i2;
    tok_w[tok * 2] = w1; tok_w[tok * 2 + 1] = 1.f - w1;
  }
}

// ---------------- count: LDS histogram, 8 global atomics per block ----------------
__global__ __launch_bounds__(256) void count_kernel(
    const int* __restrict__ tok_e, int* __restrict__ counts)
{
  __shared__ int lc[NEXP];
  if (threadIdx.x < NEXP) lc[threadIdx.x] = 0;
  __syncthreads();
  int tok = blockIdx.x * 256 + threadIdx.x;
  atomicAdd(&lc[tok_e[tok * 2]], 1);
  atomicAdd(&lc[tok_e[tok * 2 + 1]], 1);
  __syncthreads();
  if (threadIdx.x < NEXP) atomicAdd(&counts[threadIdx.x], lc[threadIdx.x]);
}

// ------- scan: pad to 256, tile table; also init pair_token to -1 -------
__global__ void scan_kernel(const int* __restrict__ counts, int* padded_off,
                            int* tile_e, int* tile_row, int* numTiles,
                            int* __restrict__ pair_token)
{
  if (blockIdx.x == 0) {
    for (int i = threadIdx.x; i < PADMAX; i += 256) pair_token[i] = -1;
    if (threadIdx.x == 0) {
      int off = 0, a = 0;
      for (int e = 0; e < NEXP; ++e) {
        padded_off[e] = off;
        int c = counts[e];
        int nt = (c + 255) / 256;
        for (int i = 0; i < nt; ++i) { tile_e[a] = e; tile_row[a] = off + i * 256; ++a; }
        off += nt * 256;
      }
      *numTiles = a;
    }
  }
}

// ---------------- scatter: LDS histogram + block-claimed ranges ----------------
__global__ __launch_bounds__(256) void scatter_kernel(
    const int* __restrict__ tok_e, const int* __restrict__ padded_off,
    int* __restrict__ fill, int* __restrict__ pair_token, int* __restrict__ tok_slot)
{
  __shared__ int lc[NEXP], lbase[NEXP];
  if (threadIdx.x < NEXP) lc[threadIdx.x] = 0;
  __syncthreads();
  int tok = blockIdx.x * 256 + threadIdx.x;
  int e0 = tok_e[tok * 2], e1 = tok_e[tok * 2 + 1];
  int r0 = atomicAdd(&lc[e0], 1);
  int r1 = atomicAdd(&lc[e1], 1);
  __syncthreads();
  if (threadIdx.x < NEXP) lbase[threadIdx.x] = atomicAdd(&fill[threadIdx.x], lc[threadIdx.x]);
  __syncthreads();
  int s0 = padded_off[e0] + lbase[e0] + r0;
  int s1 = padded_off[e1] + lbase[e1] + r1;
  pair_token[s0] = tok;
  pair_token[s1] = tok;
  tok_slot[tok * 2] = s0;
  tok_slot[tok * 2 + 1] = s1;
}

// ---------------- gather tokens -> bf16 rows (zeros for padding) ----------------
__global__ __launch_bounds__(256) void gather_x(
    const float* __restrict__ x, const int* __restrict__ pair_token,
    __hip_bfloat16* __restrict__ Xg)
{
  int gid = blockIdx.x * 256 + threadIdx.x;
  int r = gid >> 7;
  int c = (gid & 127) << 3;
  if (r >= PADMAX) return;
  int tk = pair_token[r];
  __hip_bfloat16 v[8];
  if (tk < 0) {
#pragma unroll
    for (int j = 0; j < 8; ++j) v[j] = __float2bfloat16(0.f);
  } else {
    const float* src = x + (size_t)tk * DDIM + c;
    f32x4 a = __builtin_nontemporal_load((const f32x4*)src);
    f32x4 b = __builtin_nontemporal_load((const f32x4*)(src + 4));
#pragma unroll
    for (int j = 0; j < 4; ++j) v[j] = __float2bfloat16(a[j]);
#pragma unroll
    for (int j = 0; j < 4; ++j) v[4 + j] = __float2bfloat16(b[j]);
  }
  *(us8*)(Xg + (size_t)r * DDIM + c) = *(const us8*)v;
}

// ------- fp32 (R,C) -> bf16 (C,R) transpose+convert, per expert z -------
__global__ __launch_bounds__(256) void transpose_conv(
    const float* __restrict__ in, __hip_bfloat16* __restrict__ out, int R, int C)
{
  __shared__ __hip_bfloat16 tile[64][66];   // stride 33 dwords -> conflict-free
  size_t mat = (size_t)R * C;
  const float* ip = in + (size_t)blockIdx.z * mat;
  __hip_bfloat16* op = out + (size_t)blockIdx.z * mat;
  int c0 = blockIdx.x * 64, r0 = blockIdx.y * 64;
  int tx = threadIdx.x & 31, ty = threadIdx.x >> 5;
#pragma unroll
  for (int i = 0; i < 8; ++i) {
    int r = r0 + ty + i * 8;
    f32x2 v = __builtin_nontemporal_load(
        (const f32x2*)(ip + (size_t)r * C + c0 + tx * 2));
    tile[ty + i * 8][tx * 2]     = __float2bfloat16(v[0]);
    tile[ty + i * 8][tx * 2 + 1] = __float2bfloat16(v[1]);
  }
  __syncthreads();
#pragma unroll
  for (int i = 0; i < 8; ++i) {
    int cc = c0 + ty + i * 8;
    __hip_bfloat16 a = tile[tx * 2][ty + i * 8];
    __hip_bfloat16 b = tile[tx * 2 + 1][ty + i * 8];
    unsigned short ua = *(unsigned short*)&a, ub = *(unsigned short*)&b;
    unsigned int packed = (unsigned)ua | ((unsigned)ub << 16);
    *(unsigned int*)(op + (size_t)cc * R + r0 + tx * 2) = packed;
  }
}

// ---------------- 8-phase grouped GEMM, 256x256, BK=64, read-ahead pipeline ----
// Per phase: {STAGE, counted vmcnt, barrier, ds_read frags for NEXT quadrant,
// MFMA on frags read LAST phase} -> ds_read latency hides under an MFMA cluster.
// Quadrant rotation: ph2:q00, ph3:q01, ph4:q10, ph1(kt+1):q11(kt).
template<int LD, int NT, int LDO, int NCOL, int SC, bool GELU>
__global__ __launch_bounds__(512, 2) void moe_gemm8(
    const __hip_bfloat16* __restrict__ A, const __hip_bfloat16* __restrict__ B,
    __hip_bfloat16* __restrict__ Out,
    const int* __restrict__ tile_e, const int* __restrict__ tile_row,
    const int* __restrict__ numTiles)
{
  constexpr int STU = 3 * SC;            // units per supertile
  constexpr int NCG = NCOL / SC;         // col groups
  const int bid = blockIdx.x;
  const int xcd = bid & 7;
  const int idx = bid >> 3;
  const int stg = idx / STU;
  const int within = idx % STU;
  const int colg = stg % NCG;
  const int tg = stg / NCG;
  const int tl = tg * 3 + within % 3;
  const int col = colg * SC + within / 3;
  const int nT = *numTiles;
  const int tile = ((xcd * nT) >> 3) + tl;
  if (tile >= (((xcd + 1) * nT) >> 3)) return;

  __shared__ __align__(16) __hip_bfloat16 lds[8][8192];
  const int t = threadIdx.x, lane = t & 63, w = t >> 6;
  const int wm = w >> 2, wn = w & 3;
  const int fr = lane & 15, fkg = lane >> 4;
  const size_t rowoff = (size_t)(w * 8 + (lane >> 3)) * LD + (((lane & 7) ^ (lane >> 3)) << 3);
  const int aoff = (wm * 64 + fr) * 64;
  const int boff = (wn * 32 + fr) * 64;
  const int swk0 = (fkg ^ (fr & 7)) * 8;
  const int swk1 = ((4 + fkg) ^ (fr & 7)) * 8;

  const int e = tile_e[tile];
  const int row0 = tile_row[tile];
  const int col0 = col * 256;
  const __hip_bfloat16* Ab = A + (size_t)row0 * LD;
  const __hip_bfloat16* Bb = B + (size_t)e * ((size_t)FDIM * DDIM) + (size_t)col0 * LD;

  auto STAGEH = [&](const __hip_bfloat16* base, int mat, int half, int tt) {
    __hip_bfloat16* d = &lds[(((tt & 1) << 2) | (mat << 1) | half)][0] + w * 512;
    const __hip_bfloat16* s = base + (size_t)(half * 128) * LD + (size_t)tt * 64 + rowoff;
    GLOAD16(d, s);
    GLOAD16(d + 4096, s + (size_t)64 * LD);
  };

  f32x4 acc[4][4][2] = {};
  s16x8 af0[4][2], af1[4][2], b0[2][2], b1[2][2];

  // prologue: tile 0 halves in need-order A0, B0, B1, A1
  STAGEH(Ab, 0, 0, 0); STAGEH(Bb, 1, 0, 0); STAGEH(Bb, 1, 1, 0); STAGEH(Ab, 0, 1, 0);
  // peeled ph1(0): stage A0(1), drain A0,B0(0), read af0/b0
  STAGEH(Ab, 0, 0, 1);
  WAITVM(6);
  __builtin_amdgcn_s_barrier();
  MEMFENCE;
  {
    const __hip_bfloat16* A0r = &lds[0][0];
    const __hip_bfloat16* B0r = &lds[2][0];
#pragma unroll
    for (int m = 0; m < 4; ++m) {
      af0[m][0] = *(const s16x8*)(A0r + aoff + m * 1024 + swk0);
      af0[m][1] = *(const s16x8*)(A0r + aoff + m * 1024 + swk1);
    }
#pragma unroll
    for (int n = 0; n < 2; ++n) {
      b0[n][0] = *(const s16x8*)(B0r + boff + n * 1024 + swk0);
      b0[n][1] = *(const s16x8*)(B0r + boff + n * 1024 + swk1);
    }
  }

  for (int kt = 0; kt < NT; ++kt) {
    const int buf = kt & 1;
    const bool p1 = (kt + 1) < NT;
    const bool p2 = (kt + 2) < NT;
    const __hip_bfloat16* A1r = &lds[(buf << 2) | 1][0];
    const __hip_bfloat16* B1r = &lds[(buf << 2) | 3][0];
    const __hip_bfloat16* A0n = &lds[((buf ^ 1) << 2) | 0][0];
    const __hip_bfloat16* B0n = &lds[((buf ^ 1) << 2) | 2][0];

    // ---- ph2: read B1f(kt); MFMA q00 = A0 x B0 ----
    if (p1) STAGEH(Bb, 1, 0, kt + 1);
    if (p1) { WAITVM(6); } else { WAITVM(2); }
    __builtin_amdgcn_s_barrier();
    MEMFENCE;
#pragma unroll
    for (int n = 0; n < 2; ++n) {
      b1[n][0] = *(const s16x8*)(B1r + boff + n * 1024 + swk0);
      b1[n][1] = *(const s16x8*)(B1r + boff + n * 1024 + swk1);
    }
    __builtin_amdgcn_s_setprio(1);
#pragma unroll
    for (int kk = 0; kk < 2; ++kk)
#pragma unroll
      for (int m = 0; m < 4; ++m)
#pragma unroll
        for (int n = 0; n < 2; ++n)
          acc[0][m][n] = __builtin_amdgcn_mfma_f32_16x16x32_bf16(af0[m][kk], b0[n][kk], acc[0][m][n], 0, 0, 0);
    __builtin_amdgcn_s_setprio(0);
    MEMFENCE;

    // ---- ph3: read A1f(kt); MFMA q01 = A0 x B1 ----
    if (p1) STAGEH(Bb, 1, 1, kt + 1);
    if (p1) { WAITVM(6); } else { WAITVM(0); }
    __builtin_amdgcn_s_barrier();
    MEMFENCE;
#pragma unroll
    for (int m = 0; m < 4; ++m) {
      af1[m][0] = *(const s16x8*)(A1r + aoff + m * 1024 + swk0);
      af1[m][1] = *(const s16x8*)(A1r + aoff + m * 1024 + swk1);
    }
    __builtin_amdgcn_s_setprio(1);
#pragma unroll
    for (int kk = 0; kk < 2; ++kk)
#pragma unroll
      for (int m = 0; m < 4; ++m)
#pragma unroll
        for (int n = 0; n < 2; ++n)
          acc[1][m][n] = __builtin_amdgcn_mfma_f32_16x16x32_bf16(af0[m][kk], b1[n][kk], acc[1][m][n], 0, 0, 0);
    __builtin_amdgcn_s_setprio(0);
    MEMFENCE;

    // ---- ph4: MFMA q10 = A1 x B0 (all regs resident) ----
    if (p1) STAGEH(Ab, 0, 1, kt + 1);
    __builtin_amdgcn_s_barrier();
    MEMFENCE;
    __builtin_amdgcn_s_setprio(1);
#pragma unroll
    for (int kk = 0; kk < 2; ++kk)
#pragma unroll
      for (int m = 0; m < 4; ++m)
#pragma unroll
        for (int n = 0; n < 2; ++n)
          acc[3][m][n] = __builtin_amdgcn_mfma_f32_16x16x32_bf16(af1[m][kk], b0[n][kk], acc[3][m][n], 0, 0, 0);
    __builtin_amdgcn_s_setprio(0);
    MEMFENCE;

    // ---- ph1(kt+1): read A0f,B0f(kt+1); MFMA q11(kt) = A1 x B1 ----
    if (p2) STAGEH(Ab, 0, 0, kt + 2);
    if (p1) { if (p2) { WAITVM(6); } else { WAITVM(4); } }
    __builtin_amdgcn_s_barrier();
    MEMFENCE;
    if (p1) {
#pragma unroll
      for (int m = 0; m < 4; ++m) {
        af0[m][0] = *(const s16x8*)(A0n + aoff + m * 1024 + swk0);
        af0[m][1] = *(const s16x8*)(A0n + aoff + m * 1024 + swk1);
      }
#pragma unroll
      for (int n = 0; n < 2; ++n) {
        b0[n][0] = *(const s16x8*)(B0n + boff + n * 1024 + swk0);
        b0[n][1] = *(const s16x8*)(B0n + boff + n * 1024 + swk1);
      }
    }
    __builtin_amdgcn_s_setprio(1);
#pragma unroll
    for (int kk = 0; kk < 2; ++kk)
#pragma unroll
      for (int m = 0; m < 4; ++m)
#pragma unroll
        for (int n = 0; n < 2; ++n)
          acc[2][m][n] = __builtin_amdgcn_mfma_f32_16x16x32_bf16(af1[m][kk], b1[n][kk], acc[2][m][n], 0, 0, 0);
    __builtin_amdgcn_s_setprio(0);
    MEMFENCE;
  }

  // ---- epilogue: row-major, 4 imm-offset stores per row ----
  // quadrant (qmh,qnh) -> acc idx: (0,0)=0 (0,1)=1 (1,1)=2 (1,0)=3
  const int cbase = col0 + wn * 32 + fr;
#pragma unroll
  for (int mh = 0; mh < 2; ++mh) {
    const int qa = mh ? 3 : 0;   // qnh = 0
    const int qb = mh ? 2 : 1;   // qnh = 1
#pragma unroll
    for (int m = 0; m < 4; ++m) {
#pragma unroll
      for (int j = 0; j < 4; ++j) {
        int r = row0 + mh * 128 + wm * 64 + m * 16 + fkg * 4 + j;
        __hip_bfloat16* p = Out + (size_t)r * LDO + cbase;
        float v0 = acc[qa][m][0][j];
        float v1 = acc[qa][m][1][j];
        float v2 = acc[qb][m][0][j];
        float v3 = acc[qb][m][1][j];
        if (GELU) {
          v0 = gelu_fast(v0); v1 = gelu_fast(v1);
          v2 = gelu_fast(v2); v3 = gelu_fast(v3);
        }
        p[0]   = __float2bfloat16(v0);
        p[16]  = __float2bfloat16(v1);
        p[128] = __float2bfloat16(v2);
        p[144] = __float2bfloat16(v3);
      }
    }
  }
}

// ---------------- combine: out[tok] = wa*Eout[sa] + wb*Eout[sb] ----------------
__global__ __launch_bounds__(256) void combine_kernel(
    const __hip_bfloat16* __restrict__ Eout, const int* __restrict__ tok_slot,
    const float* __restrict__ tok_w, float* __restrict__ out)
{
  int tok = blockIdx.x;
  int sa = tok_slot[tok * 2], sb = tok_slot[tok * 2 + 1];
  float wa = tok_w[tok * 2], wb = tok_w[tok * 2 + 1];
  const __hip_bfloat16* ra = Eout + (size_t)sa * DDIM;
  const __hip_bfloat16* rb = Eout + (size_t)sb * DDIM;
  float* op = out + (size_t)tok * DDIM;
  int c = threadIdx.x * 4;
  us4 va = *(const us4*)(ra + c);
  us4 vb = *(const us4*)(rb + c);
  float4 o;
  o.x = wa * bf2f(va.x) + wb * bf2f(vb.x);
  o.y = wa * bf2f(va.y) + wb * bf2f(vb.y);
  o.z = wa * bf2f(va.z) + wb * bf2f(vb.z);
  o.w = wa * bf2f(va.w) + wb * bf2f(vb.w);
  *(float4*)(op + c) = o;
}

extern "C" void kernel_launch(void* const* d_in, const int* in_sizes, int n_in,
                              void* d_out, int out_size, void* d_ws, size_t ws_size,
                              hipStream_t stream)
{
  const float* x      = (const float*)d_in[0];
  const float* gate_w = (const float*)d_in[1];
  const float* w1     = (const float*)d_in[2];
  const float* w2     = (const float*)d_in[3];
  float* out = (float*)d_out;

  char* ws = (char*)d_ws;
  size_t off = 0;
  auto alloc = [&](size_t bytes) -> void* {
    void* p = ws + off;
    off = (off + bytes + 255) & ~(size_t)255;
    return p;
  };
  int* ctrl = (int*)alloc(1024);          // zeroed control block
  int* counts     = ctrl + 0;
  int* fill       = ctrl + 8;
  int* padded_off = ctrl + 16;
  int* numTiles   = ctrl + 24;
  int*   tile_e     = (int*)alloc(MAXT * 4);
  int*   tile_row   = (int*)alloc(MAXT * 4);
  int*   tok_e      = (int*)alloc((size_t)T_TOK * 2 * 4);
  float* tok_w      = (float*)alloc((size_t)T_TOK * 2 * 4);
  int*   tok_slot   = (int*)alloc((size_t)T_TOK * 2 * 4);
  int*   pair_token = (int*)alloc((size_t)PADMAX * 4);
  __hip_bfloat16* XgEout = (__hip_bfloat16*)alloc((size_t)PADMAX * DDIM * 2); // Xg, later Eout
  __hip_bfloat16* W1t  = (__hip_bfloat16*)alloc((size_t)NEXP * FDIM * DDIM * 2);
  __hip_bfloat16* W2t  = (__hip_bfloat16*)alloc((size_t)NEXP * FDIM * DDIM * 2);
  __hip_bfloat16* Hbuf = (__hip_bfloat16*)alloc((size_t)PADMAX * FDIM * 2);
  (void)in_sizes; (void)n_in; (void)ws_size; (void)out_size;

  (void)hipMemsetAsync(d_ws, 0, 1024, stream);

  gate_kernel<<<T_TOK / 4, 256, 0, stream>>>(x, gate_w, tok_e, tok_w);
  count_kernel<<<T_TOK / 256, 256, 0, stream>>>(tok_e, counts);
  scan_kernel<<<1, 256, 0, stream>>>(counts, padded_off, tile_e, tile_row, numTiles,
                                     pair_token);
  scatter_kernel<<<T_TOK / 256, 256, 0, stream>>>(tok_e, padded_off, fill,
                                                  pair_token, tok_slot);
  gather_x<<<(PADMAX * (DDIM / 8) + 255) / 256, 256, 0, stream>>>(x, pair_token, XgEout);

  transpose_conv<<<dim3(FDIM / 64, DDIM / 64, NEXP), 256, 0, stream>>>(w1, W1t, DDIM, FDIM);

  // ffn1: H = gelu(Xg @ W1t[e]^T)   (K=1024, N=4096)
  moe_gemm8<DDIM, DDIM / 64, FDIM, FDIM / 256, 8, true>
      <<<MAXT * (FDIM / 256), 512, 0, stream>>>(XgEout, W1t, Hbuf,
                                                tile_e, tile_row, numTiles);

  transpose_conv<<<dim3(DDIM / 64, FDIM / 64, NEXP), 256, 0, stream>>>(w2, W2t, FDIM, DDIM);

  // ffn2: Eout = H @ W2t[e]^T       (K=4096, N=1024)
  moe_gemm8<FDIM, FDIM / 64, DDIM, DDIM / 256, 4, false>
      <<<MAXT * (DDIM / 256), 512, 0, stream>>>(Hbuf, W2t, XgEout,
                                                tile_e, tile_row, numTiles);

  combine_kernel<<<T_TOK, 256, 0, stream>>>(XgEout, tok_slot, tok_w, out);
}

// Round 12
// 472.311 us; speedup vs baseline: 1.5969x; 1.0285x over previous
//
#include <hip/hip_runtime.h>
#include <hip/hip_bf16.h>

typedef short s16x8 __attribute__((ext_vector_type(8)));
typedef float f32x4 __attribute__((ext_vector_type(4)));
typedef float f32x2 __attribute__((ext_vector_type(2)));
typedef unsigned short us8 __attribute__((ext_vector_type(8)));
typedef unsigned short us4 __attribute__((ext_vector_type(4)));

#define T_TOK 8192
#define DDIM 1024
#define NEXP 8
#define FDIM 4096
#define MAXT 72
#define PADMAX (16384 + NEXP * 256)
#define GATHB ((PADMAX * 128) / 256)      // 9216 gather blocks
#define TR1B 8192                          // w1 transpose blocks (256t, 64x64)
#define TR2B 4096                          // w2 transpose blocks (512t, 2x 64x64)

#define GLOAD16(dst, src) \
  __builtin_amdgcn_global_load_lds((const __attribute__((address_space(1))) unsigned int*)(src), \
                                   (__attribute__((address_space(3))) unsigned int*)(dst), 16, 0, 0)
#define WAITVM(n) asm volatile("s_waitcnt vmcnt(" #n ")" ::: "memory")
#define MEMFENCE asm volatile("" ::: "memory")

__device__ __forceinline__ float gelu_fast(float x) {
  float x2 = x * x;
  float t = x * fmaf(x2, -0.07135532f, -1.5957691f);
  float e = __expf(t);
  return x * __builtin_amdgcn_rcpf(1.0f + e);
}
__device__ __forceinline__ float bf2f(unsigned short v) {
  return __uint_as_float((unsigned)v << 16);
}

// ---- shared 64x64 fp32->bf16 transpose subtile body (one 256-thread group) ----
__device__ __forceinline__ void trans64(const float* __restrict__ ip,
                                        __hip_bfloat16* __restrict__ op,
                                        int R, int C, int c0, int r0, int tid,
                                        __hip_bfloat16 (*tile)[66]) {
  int tx = tid & 31, ty = tid >> 5;
#pragma unroll
  for (int i = 0; i < 8; ++i) {
    int r = r0 + ty + i * 8;
    f32x2 v = __builtin_nontemporal_load(
        (const f32x2*)(ip + (size_t)r * C + c0 + tx * 2));
    tile[ty + i * 8][tx * 2]     = __float2bfloat16(v[0]);
    tile[ty + i * 8][tx * 2 + 1] = __float2bfloat16(v[1]);
  }
  __syncthreads();
#pragma unroll
  for (int i = 0; i < 8; ++i) {
    int cc = c0 + ty + i * 8;
    __hip_bfloat16 a = tile[tx * 2][ty + i * 8];
    __hip_bfloat16 b = tile[tx * 2 + 1][ty + i * 8];
    unsigned short ua = *(unsigned short*)&a, ub = *(unsigned short*)&b;
    unsigned int packed = (unsigned)ua | ((unsigned)ub << 16);
    *(unsigned int*)(op + (size_t)cc * R + r0 + tx * 2) = packed;
  }
}

// ---------------- gating (no atomics) ----------------
__global__ __launch_bounds__(256) void gate_kernel(
    const float* __restrict__ x, const float* __restrict__ gw,
    int* __restrict__ tok_e, float* __restrict__ tok_w)
{
  int lane = threadIdx.x & 63;
  int tok = blockIdx.x * 4 + (threadIdx.x >> 6);
  const float* xr = x + (size_t)tok * DDIM;
  float acc[NEXP];
#pragma unroll
  for (int e = 0; e < NEXP; ++e) acc[e] = 0.f;
  for (int i = 0; i < DDIM / 64; ++i) {
    int d = i * 64 + lane;
    float xv = xr[d];
    const float* g = gw + (size_t)d * NEXP;
#pragma unroll
    for (int e = 0; e < NEXP; ++e) acc[e] += xv * g[e];
  }
#pragma unroll
  for (int off = 32; off > 0; off >>= 1) {
#pragma unroll
    for (int e = 0; e < NEXP; ++e) acc[e] += __shfl_xor(acc[e], off);
  }
  if (lane == 0) {
    int i1 = 0; float m1 = acc[0];
#pragma unroll
    for (int e = 1; e < NEXP; ++e) if (acc[e] > m1) { m1 = acc[e]; i1 = e; }
    int i2 = -1; float m2 = -3.4e38f;
#pragma unroll
    for (int e = 0; e < NEXP; ++e) if (e != i1 && acc[e] > m2) { m2 = acc[e]; i2 = e; }
    float w1 = 1.f / (1.f + expf(m2 - m1));
    tok_e[tok * 2] = i1; tok_e[tok * 2 + 1] = i2;
    tok_w[tok * 2] = w1; tok_w[tok * 2 + 1] = 1.f - w1;
  }
}

// ---------------- count: LDS histogram ----------------
__global__ __launch_bounds__(256) void count_kernel(
    const int* __restrict__ tok_e, int* __restrict__ counts)
{
  __shared__ int lc[NEXP];
  if (threadIdx.x < NEXP) lc[threadIdx.x] = 0;
  __syncthreads();
  int tok = blockIdx.x * 256 + threadIdx.x;
  atomicAdd(&lc[tok_e[tok * 2]], 1);
  atomicAdd(&lc[tok_e[tok * 2 + 1]], 1);
  __syncthreads();
  if (threadIdx.x < NEXP) atomicAdd(&counts[threadIdx.x], lc[threadIdx.x]);
}

// ------- scan: pad to 256, tile table; init pair_token -------
__global__ void scan_kernel(const int* __restrict__ counts, int* padded_off,
                            int* tile_e, int* tile_row, int* numTiles,
                            int* __restrict__ pair_token)
{
  if (blockIdx.x == 0) {
    for (int i = threadIdx.x; i < PADMAX; i += 256) pair_token[i] = -1;
    if (threadIdx.x == 0) {
      int off = 0, a = 0;
      for (int e = 0; e < NEXP; ++e) {
        padded_off[e] = off;
        int c = counts[e];
        int nt = (c + 255) / 256;
        for (int i = 0; i < nt; ++i) { tile_e[a] = e; tile_row[a] = off + i * 256; ++a; }
        off += nt * 256;
      }
      *numTiles = a;
    }
  }
}

// ---------------- scatter: LDS histogram + block-claimed ranges ----------------
__global__ __launch_bounds__(256) void scatter_kernel(
    const int* __restrict__ tok_e, const int* __restrict__ padded_off,
    int* __restrict__ fill, int* __restrict__ pair_token, int* __restrict__ tok_slot)
{
  __shared__ int lc[NEXP], lbase[NEXP];
  if (threadIdx.x < NEXP) lc[threadIdx.x] = 0;
  __syncthreads();
  int tok = blockIdx.x * 256 + threadIdx.x;
  int e0 = tok_e[tok * 2], e1 = tok_e[tok * 2 + 1];
  int r0 = atomicAdd(&lc[e0], 1);
  int r1 = atomicAdd(&lc[e1], 1);
  __syncthreads();
  if (threadIdx.x < NEXP) lbase[threadIdx.x] = atomicAdd(&fill[threadIdx.x], lc[threadIdx.x]);
  __syncthreads();
  int s0 = padded_off[e0] + lbase[e0] + r0;
  int s1 = padded_off[e1] + lbase[e1] + r1;
  pair_token[s0] = tok;
  pair_token[s1] = tok;
  tok_slot[tok * 2] = s0;
  tok_slot[tok * 2 + 1] = s1;
}

// -------- fused: gather tokens -> bf16 rows  ||  w1 fp32 transpose -> W1t --------
__global__ __launch_bounds__(256) void gather_trans1(
    const float* __restrict__ x, const int* __restrict__ pair_token,
    __hip_bfloat16* __restrict__ Xg,
    const float* __restrict__ w1, __hip_bfloat16* __restrict__ W1t)
{
  __shared__ __hip_bfloat16 tile[64][66];
  int bid = blockIdx.x;
  if (bid >= GATHB) {
    // w1: in (R=DDIM, C=FDIM) per expert -> out (C,R)
    int i = bid - GATHB;                 // [0, 8192)
    int xq = i & 63, yq = (i >> 6) & 15, z = i >> 10;
    size_t mat = (size_t)DDIM * FDIM;
    trans64(w1 + (size_t)z * mat, W1t + (size_t)z * mat,
            DDIM, FDIM, xq * 64, yq * 64, threadIdx.x, tile);
    return;
  }
  int gid = bid * 256 + threadIdx.x;
  int r = gid >> 7;
  int c = (gid & 127) << 3;
  if (r >= PADMAX) return;
  int tk = pair_token[r];
  __hip_bfloat16 v[8];
  if (tk < 0) {
#pragma unroll
    for (int j = 0; j < 8; ++j) v[j] = __float2bfloat16(0.f);
  } else {
    const float* src = x + (size_t)tk * DDIM + c;
    f32x4 a = __builtin_nontemporal_load((const f32x4*)src);
    f32x4 b = __builtin_nontemporal_load((const f32x4*)(src + 4));
#pragma unroll
    for (int j = 0; j < 4; ++j) v[j] = __float2bfloat16(a[j]);
#pragma unroll
    for (int j = 0; j < 4; ++j) v[4 + j] = __float2bfloat16(b[j]);
  }
  *(us8*)(Xg + (size_t)r * DDIM + c) = *(const us8*)v;
}

// ---------------- 8-phase grouped GEMM, 256x256, BK=64, read-ahead pipeline ----
// FUSET: trailing grid blocks transpose w2 -> W2t (tail-fill during GEMM idle).
template<int LD, int NT, int LDO, int NCOL, int SC, bool GELU, bool FUSET>
__global__ __launch_bounds__(512, 2) void moe_gemm8(
    const __hip_bfloat16* __restrict__ A, const __hip_bfloat16* __restrict__ B,
    __hip_bfloat16* __restrict__ Out,
    const int* __restrict__ tile_e, const int* __restrict__ tile_row,
    const int* __restrict__ numTiles,
    const float* __restrict__ w2, __hip_bfloat16* __restrict__ W2t)
{
  __shared__ __align__(16) __hip_bfloat16 lds[8][8192];
  if (FUSET && (int)blockIdx.x >= MAXT * NCOL) {
    // w2: in (R=FDIM, C=DDIM) per expert -> out (C,R); 2 subtiles per 512t block
    int i2 = ((int)blockIdx.x - MAXT * NCOL) * 2 + (threadIdx.x >> 8);  // [0,8192)
    int xq = i2 & 15, yq = (i2 >> 4) & 63, z = i2 >> 10;
    int sub = threadIdx.x >> 8, tid = threadIdx.x & 255;
    __hip_bfloat16 (*tile)[66] =
        reinterpret_cast<__hip_bfloat16(*)[66]>(&lds[0][0] + sub * 64 * 66);
    size_t mat = (size_t)FDIM * DDIM;
    trans64(w2 + (size_t)z * mat, W2t + (size_t)z * mat,
            FDIM, DDIM, xq * 64, yq * 64, tid, tile);
    return;
  }
  constexpr int STU = 3 * SC;
  constexpr int NCG = NCOL / SC;
  const int bid = blockIdx.x;
  const int xcd = bid & 7;
  const int idx = bid >> 3;
  const int stg = idx / STU;
  const int within = idx % STU;
  const int colg = stg % NCG;
  const int tg = stg / NCG;
  const int tl = tg * 3 + within % 3;
  const int col = colg * SC + within / 3;
  const int nT = *numTiles;
  const int tile = ((xcd * nT) >> 3) + tl;
  if (tile >= (((xcd + 1) * nT) >> 3)) return;

  const int t = threadIdx.x, lane = t & 63, w = t >> 6;
  const int wm = w >> 2, wn = w & 3;
  const int fr = lane & 15, fkg = lane >> 4;
  const size_t rowoff = (size_t)(w * 8 + (lane >> 3)) * LD + (((lane & 7) ^ (lane >> 3)) << 3);
  const int aoff = (wm * 64 + fr) * 64;
  const int boff = (wn * 32 + fr) * 64;
  const int swk0 = (fkg ^ (fr & 7)) * 8;
  const int swk1 = ((4 + fkg) ^ (fr & 7)) * 8;

  const int e = tile_e[tile];
  const int row0 = tile_row[tile];
  const int col0 = col * 256;
  const __hip_bfloat16* Ab = A + (size_t)row0 * LD;
  const __hip_bfloat16* Bb = B + (size_t)e * ((size_t)FDIM * DDIM) + (size_t)col0 * LD;

  auto STAGEH = [&](const __hip_bfloat16* base, int mat, int half, int tt) {
    __hip_bfloat16* d = &lds[(((tt & 1) << 2) | (mat << 1) | half)][0] + w * 512;
    const __hip_bfloat16* s = base + (size_t)(half * 128) * LD + (size_t)tt * 64 + rowoff;
    GLOAD16(d, s);
    GLOAD16(d + 4096, s + (size_t)64 * LD);
  };

  f32x4 acc[4][4][2] = {};
  s16x8 af0[4][2], af1[4][2], b0[2][2], b1[2][2];

  STAGEH(Ab, 0, 0, 0); STAGEH(Bb, 1, 0, 0); STAGEH(Bb, 1, 1, 0); STAGEH(Ab, 0, 1, 0);
  STAGEH(Ab, 0, 0, 1);
  WAITVM(6);
  __builtin_amdgcn_s_barrier();
  MEMFENCE;
  {
    const __hip_bfloat16* A0r = &lds[0][0];
    const __hip_bfloat16* B0r = &lds[2][0];
#pragma unroll
    for (int m = 0; m < 4; ++m) {
      af0[m][0] = *(const s16x8*)(A0r + aoff + m * 1024 + swk0);
      af0[m][1] = *(const s16x8*)(A0r + aoff + m * 1024 + swk1);
    }
#pragma unroll
    for (int n = 0; n < 2; ++n) {
      b0[n][0] = *(const s16x8*)(B0r + boff + n * 1024 + swk0);
      b0[n][1] = *(const s16x8*)(B0r + boff + n * 1024 + swk1);
    }
  }

  for (int kt = 0; kt < NT; ++kt) {
    const int buf = kt & 1;
    const bool p1 = (kt + 1) < NT;
    const bool p2 = (kt + 2) < NT;
    const __hip_bfloat16* A1r = &lds[(buf << 2) | 1][0];
    const __hip_bfloat16* B1r = &lds[(buf << 2) | 3][0];
    const __hip_bfloat16* A0n = &lds[((buf ^ 1) << 2) | 0][0];
    const __hip_bfloat16* B0n = &lds[((buf ^ 1) << 2) | 2][0];

    // ---- ph2: read B1f(kt); MFMA q00 ----
    if (p1) STAGEH(Bb, 1, 0, kt + 1);
    if (p1) { WAITVM(6); } else { WAITVM(2); }
    __builtin_amdgcn_s_barrier();
    MEMFENCE;
#pragma unroll
    for (int n = 0; n < 2; ++n) {
      b1[n][0] = *(const s16x8*)(B1r + boff + n * 1024 + swk0);
      b1[n][1] = *(const s16x8*)(B1r + boff + n * 1024 + swk1);
    }
    __builtin_amdgcn_s_setprio(1);
#pragma unroll
    for (int kk = 0; kk < 2; ++kk)
#pragma unroll
      for (int m = 0; m < 4; ++m)
#pragma unroll
        for (int n = 0; n < 2; ++n)
          acc[0][m][n] = __builtin_amdgcn_mfma_f32_16x16x32_bf16(af0[m][kk], b0[n][kk], acc[0][m][n], 0, 0, 0);
    __builtin_amdgcn_s_setprio(0);
    MEMFENCE;

    // ---- ph3: read A1f(kt); MFMA q01 ----
    if (p1) STAGEH(Bb, 1, 1, kt + 1);
    if (p1) { WAITVM(6); } else { WAITVM(0); }
    __builtin_amdgcn_s_barrier();
    MEMFENCE;
#pragma unroll
    for (int m = 0; m < 4; ++m) {
      af1[m][0] = *(const s16x8*)(A1r + aoff + m * 1024 + swk0);
      af1[m][1] = *(const s16x8*)(A1r + aoff + m * 1024 + swk1);
    }
    __builtin_amdgcn_s_setprio(1);
#pragma unroll
    for (int kk = 0; kk < 2; ++kk)
#pragma unroll
      for (int m = 0; m < 4; ++m)
#pragma unroll
        for (int n = 0; n < 2; ++n)
          acc[1][m][n] = __builtin_amdgcn_mfma_f32_16x16x32_bf16(af0[m][kk], b1[n][kk], acc[1][m][n], 0, 0, 0);
    __builtin_amdgcn_s_setprio(0);
    MEMFENCE;

    // ---- ph4: MFMA q10 ----
    if (p1) STAGEH(Ab, 0, 1, kt + 1);
    __builtin_amdgcn_s_barrier();
    MEMFENCE;
    __builtin_amdgcn_s_setprio(1);
#pragma unroll
    for (int kk = 0; kk < 2; ++kk)
#pragma unroll
      for (int m = 0; m < 4; ++m)
#pragma unroll
        for (int n = 0; n < 2; ++n)
          acc[3][m][n] = __builtin_amdgcn_mfma_f32_16x16x32_bf16(af1[m][kk], b0[n][kk], acc[3][m][n], 0, 0, 0);
    __builtin_amdgcn_s_setprio(0);
    MEMFENCE;

    // ---- ph1(kt+1): read A0f,B0f(kt+1); MFMA q11(kt) ----
    if (p2) STAGEH(Ab, 0, 0, kt + 2);
    if (p1) { if (p2) { WAITVM(6); } else { WAITVM(4); } }
    __builtin_amdgcn_s_barrier();
    MEMFENCE;
    if (p1) {
#pragma unroll
      for (int m = 0; m < 4; ++m) {
        af0[m][0] = *(const s16x8*)(A0n + aoff + m * 1024 + swk0);
        af0[m][1] = *(const s16x8*)(A0n + aoff + m * 1024 + swk1);
      }
#pragma unroll
      for (int n = 0; n < 2; ++n) {
        b0[n][0] = *(const s16x8*)(B0n + boff + n * 1024 + swk0);
        b0[n][1] = *(const s16x8*)(B0n + boff + n * 1024 + swk1);
      }
    }
    __builtin_amdgcn_s_setprio(1);
#pragma unroll
    for (int kk = 0; kk < 2; ++kk)
#pragma unroll
      for (int m = 0; m < 4; ++m)
#pragma unroll
        for (int n = 0; n < 2; ++n)
          acc[2][m][n] = __builtin_amdgcn_mfma_f32_16x16x32_bf16(af1[m][kk], b1[n][kk], acc[2][m][n], 0, 0, 0);
    __builtin_amdgcn_s_setprio(0);
    MEMFENCE;
  }

  // ---- epilogue ----
  const int cbase = col0 + wn * 32 + fr;
#pragma unroll
  for (int mh = 0; mh < 2; ++mh) {
    const int qa = mh ? 3 : 0;
    const int qb = mh ? 2 : 1;
#pragma unroll
    for (int m = 0; m < 4; ++m) {
#pragma unroll
      for (int j = 0; j < 4; ++j) {
        int r = row0 + mh * 128 + wm * 64 + m * 16 + fkg * 4 + j;
        __hip_bfloat16* p = Out + (size_t)r * LDO + cbase;
        float v0 = acc[qa][m][0][j];
        float v1 = acc[qa][m][1][j];
        float v2 = acc[qb][m][0][j];
        float v3 = acc[qb][m][1][j];
        if (GELU) {
          v0 = gelu_fast(v0); v1 = gelu_fast(v1);
          v2 = gelu_fast(v2); v3 = gelu_fast(v3);
        }
        p[0]   = __float2bfloat16(v0);
        p[16]  = __float2bfloat16(v1);
        p[128] = __float2bfloat16(v2);
        p[144] = __float2bfloat16(v3);
      }
    }
  }
}

// ---------------- combine ----------------
__global__ __launch_bounds__(256) void combine_kernel(
    const __hip_bfloat16* __restrict__ Eout, const int* __restrict__ tok_slot,
    const float* __restrict__ tok_w, float* __restrict__ out)
{
  int tok = blockIdx.x;
  int sa = tok_slot[tok * 2], sb = tok_slot[tok * 2 + 1];
  float wa = tok_w[tok * 2], wb = tok_w[tok * 2 + 1];
  const __hip_bfloat16* ra = Eout + (size_t)sa * DDIM;
  const __hip_bfloat16* rb = Eout + (size_t)sb * DDIM;
  float* op = out + (size_t)tok * DDIM;
  int c = threadIdx.x * 4;
  us4 va = *(const us4*)(ra + c);
  us4 vb = *(const us4*)(rb + c);
  float4 o;
  o.x = wa * bf2f(va.x) + wb * bf2f(vb.x);
  o.y = wa * bf2f(va.y) + wb * bf2f(vb.y);
  o.z = wa * bf2f(va.z) + wb * bf2f(vb.z);
  o.w = wa * bf2f(va.w) + wb * bf2f(vb.w);
  *(float4*)(op + c) = o;
}

extern "C" void kernel_launch(void* const* d_in, const int* in_sizes, int n_in,
                              void* d_out, int out_size, void* d_ws, size_t ws_size,
                              hipStream_t stream)
{
  const float* x      = (const float*)d_in[0];
  const float* gate_w = (const float*)d_in[1];
  const float* w1     = (const float*)d_in[2];
  const float* w2     = (const float*)d_in[3];
  float* out = (float*)d_out;

  char* ws = (char*)d_ws;
  size_t off = 0;
  auto alloc = [&](size_t bytes) -> void* {
    void* p = ws + off;
    off = (off + bytes + 255) & ~(size_t)255;
    return p;
  };
  int* ctrl = (int*)alloc(1024);
  int* counts     = ctrl + 0;
  int* fill       = ctrl + 8;
  int* padded_off = ctrl + 16;
  int* numTiles   = ctrl + 24;
  int*   tile_e     = (int*)alloc(MAXT * 4);
  int*   tile_row   = (int*)alloc(MAXT * 4);
  int*   tok_e      = (int*)alloc((size_t)T_TOK * 2 * 4);
  float* tok_w      = (float*)alloc((size_t)T_TOK * 2 * 4);
  int*   tok_slot   = (int*)alloc((size_t)T_TOK * 2 * 4);
  int*   pair_token = (int*)alloc((size_t)PADMAX * 4);
  __hip_bfloat16* XgEout = (__hip_bfloat16*)alloc((size_t)PADMAX * DDIM * 2);
  __hip_bfloat16* W1t  = (__hip_bfloat16*)alloc((size_t)NEXP * FDIM * DDIM * 2);
  __hip_bfloat16* W2t  = (__hip_bfloat16*)alloc((size_t)NEXP * FDIM * DDIM * 2);
  __hip_bfloat16* Hbuf = (__hip_bfloat16*)alloc((size_t)PADMAX * FDIM * 2);
  (void)in_sizes; (void)n_in; (void)ws_size; (void)out_size;

  (void)hipMemsetAsync(d_ws, 0, 1024, stream);

  gate_kernel<<<T_TOK / 4, 256, 0, stream>>>(x, gate_w, tok_e, tok_w);
  count_kernel<<<T_TOK / 256, 256, 0, stream>>>(tok_e, counts);
  scan_kernel<<<1, 256, 0, stream>>>(counts, padded_off, tile_e, tile_row, numTiles,
                                     pair_token);
  scatter_kernel<<<T_TOK / 256, 256, 0, stream>>>(tok_e, padded_off, fill,
                                                  pair_token, tok_slot);
  // fused: token gather || w1 transpose
  gather_trans1<<<GATHB + TR1B, 256, 0, stream>>>(x, pair_token, XgEout, w1, W1t);

  // ffn1 (K=1024, N=4096) fused with w2 transpose (tail-fill)
  moe_gemm8<DDIM, DDIM / 64, FDIM, FDIM / 256, 8, true, true>
      <<<MAXT * (FDIM / 256) + TR2B, 512, 0, stream>>>(XgEout, W1t, Hbuf,
                                                       tile_e, tile_row, numTiles,
                                                       w2, W2t);
  // ffn2 (K=4096, N=1024)
  moe_gemm8<FDIM, FDIM / 64, DDIM, DDIM / 256, 4, false, false>
      <<<MAXT * (DDIM / 256), 512, 0, stream>>>(Hbuf, W2t, XgEout,
                                                tile_e, tile_row, numTiles,
                                                nullptr, nullptr);

  combine_kernel<<<T_TOK, 256, 0, stream>>>(XgEout, tok_slot, tok_w, out);
}

// Round 14
// 451.445 us; speedup vs baseline: 1.6707x; 1.0462x over previous
//
#include <hip/hip_runtime.h>
#include <hip/hip_bf16.h>

typedef short s16x8 __attribute__((ext_vector_type(8)));
typedef float f32x4 __attribute__((ext_vector_type(4)));
typedef float f32x2 __attribute__((ext_vector_type(2)));
typedef unsigned short us8 __attribute__((ext_vector_type(8)));
typedef unsigned short us4 __attribute__((ext_vector_type(4)));

#define T_TOK 8192
#define DDIM 1024
#define NEXP 8
#define FDIM 4096
#define MAXT 72
#define PADMAX (16384 + NEXP * 256)
#define GATHB ((PADMAX * 128) / 256)      // 9216 gather blocks
#define TR1B 8192                          // w1 transpose blocks (256t, 64x64)
#define TR2B 4096                          // w2 transpose blocks (512t, 2x 64x64)

#define GLOAD16(dst, src) \
  __builtin_amdgcn_global_load_lds((const __attribute__((address_space(1))) unsigned int*)(src), \
                                   (__attribute__((address_space(3))) unsigned int*)(dst), 16, 0, 0)
#define WAITVM(n) asm volatile("s_waitcnt vmcnt(" #n ")" ::: "memory")
#define MEMFENCE asm volatile("" ::: "memory")

__device__ __forceinline__ float gelu_fast(float x) {
  float x2 = x * x;
  float t = x * fmaf(x2, -0.07135532f, -1.5957691f);
  float e = __expf(t);
  return x * __builtin_amdgcn_rcpf(1.0f + e);
}
__device__ __forceinline__ float bf2f(unsigned short v) {
  return __uint_as_float((unsigned)v << 16);
}

// ---- shared 64x64 fp32->bf16 transpose subtile body ----
__device__ __forceinline__ void trans64(const float* __restrict__ ip,
                                        __hip_bfloat16* __restrict__ op,
                                        int R, int C, int c0, int r0, int tid,
                                        __hip_bfloat16 (*tile)[66]) {
  int tx = tid & 31, ty = tid >> 5;
#pragma unroll
  for (int i = 0; i < 8; ++i) {
    int r = r0 + ty + i * 8;
    f32x2 v = __builtin_nontemporal_load(
        (const f32x2*)(ip + (size_t)r * C + c0 + tx * 2));
    tile[ty + i * 8][tx * 2]     = __float2bfloat16(v[0]);
    tile[ty + i * 8][tx * 2 + 1] = __float2bfloat16(v[1]);
  }
  __syncthreads();
#pragma unroll
  for (int i = 0; i < 8; ++i) {
    int cc = c0 + ty + i * 8;
    __hip_bfloat16 a = tile[tx * 2][ty + i * 8];
    __hip_bfloat16 b = tile[tx * 2 + 1][ty + i * 8];
    unsigned short ua = *(unsigned short*)&a, ub = *(unsigned short*)&b;
    unsigned int packed = (unsigned)ua | ((unsigned)ub << 16);
    *(unsigned int*)(op + (size_t)cc * R + r0 + tx * 2) = packed;
  }
}

// ---------------- gating (no atomics) ----------------
__global__ __launch_bounds__(256) void gate_kernel(
    const float* __restrict__ x, const float* __restrict__ gw,
    int* __restrict__ tok_e, float* __restrict__ tok_w)
{
  int lane = threadIdx.x & 63;
  int tok = blockIdx.x * 4 + (threadIdx.x >> 6);
  const float* xr = x + (size_t)tok * DDIM;
  float acc[NEXP];
#pragma unroll
  for (int e = 0; e < NEXP; ++e) acc[e] = 0.f;
  for (int i = 0; i < DDIM / 64; ++i) {
    int d = i * 64 + lane;
    float xv = xr[d];
    const float* g = gw + (size_t)d * NEXP;
#pragma unroll
    for (int e = 0; e < NEXP; ++e) acc[e] += xv * g[e];
  }
#pragma unroll
  for (int off = 32; off > 0; off >>= 1) {
#pragma unroll
    for (int e = 0; e < NEXP; ++e) acc[e] += __shfl_xor(acc[e], off);
  }
  if (lane == 0) {
    int i1 = 0; float m1 = acc[0];
#pragma unroll
    for (int e = 1; e < NEXP; ++e) if (acc[e] > m1) { m1 = acc[e]; i1 = e; }
    int i2 = -1; float m2 = -3.4e38f;
#pragma unroll
    for (int e = 0; e < NEXP; ++e) if (e != i1 && acc[e] > m2) { m2 = acc[e]; i2 = e; }
    float w1 = 1.f / (1.f + expf(m2 - m1));
    tok_e[tok * 2] = i1; tok_e[tok * 2 + 1] = i2;
    tok_w[tok * 2] = w1; tok_w[tok * 2 + 1] = 1.f - w1;
  }
}

// ---------------- count: LDS histogram ----------------
__global__ __launch_bounds__(256) void count_kernel(
    const int* __restrict__ tok_e, int* __restrict__ counts)
{
  __shared__ int lc[NEXP];
  if (threadIdx.x < NEXP) lc[threadIdx.x] = 0;
  __syncthreads();
  int tok = blockIdx.x * 256 + threadIdx.x;
  atomicAdd(&lc[tok_e[tok * 2]], 1);
  atomicAdd(&lc[tok_e[tok * 2 + 1]], 1);
  __syncthreads();
  if (threadIdx.x < NEXP) atomicAdd(&counts[threadIdx.x], lc[threadIdx.x]);
}

// ------- scan: pad to 256, tile table; init pair_token -------
__global__ void scan_kernel(const int* __restrict__ counts, int* padded_off,
                            int* tile_e, int* tile_row, int* numTiles,
                            int* __restrict__ pair_token)
{
  if (blockIdx.x == 0) {
    for (int i = threadIdx.x; i < PADMAX; i += 256) pair_token[i] = -1;
    if (threadIdx.x == 0) {
      int off = 0, a = 0;
      for (int e = 0; e < NEXP; ++e) {
        padded_off[e] = off;
        int c = counts[e];
        int nt = (c + 255) / 256;
        for (int i = 0; i < nt; ++i) { tile_e[a] = e; tile_row[a] = off + i * 256; ++a; }
        off += nt * 256;
      }
      *numTiles = a;
    }
  }
}

// ---------------- scatter: LDS histogram + block-claimed ranges ----------------
__global__ __launch_bounds__(256) void scatter_kernel(
    const int* __restrict__ tok_e, const int* __restrict__ padded_off,
    int* __restrict__ fill, int* __restrict__ pair_token, int* __restrict__ tok_slot)
{
  __shared__ int lc[NEXP], lbase[NEXP];
  if (threadIdx.x < NEXP) lc[threadIdx.x] = 0;
  __syncthreads();
  int tok = blockIdx.x * 256 + threadIdx.x;
  int e0 = tok_e[tok * 2], e1 = tok_e[tok * 2 + 1];
  int r0 = atomicAdd(&lc[e0], 1);
  int r1 = atomicAdd(&lc[e1], 1);
  __syncthreads();
  if (threadIdx.x < NEXP) lbase[threadIdx.x] = atomicAdd(&fill[threadIdx.x], lc[threadIdx.x]);
  __syncthreads();
  int s0 = padded_off[e0] + lbase[e0] + r0;
  int s1 = padded_off[e1] + lbase[e1] + r1;
  pair_token[s0] = tok;
  pair_token[s1] = tok;
  tok_slot[tok * 2] = s0;
  tok_slot[tok * 2 + 1] = s1;
}

// -------- fused: gather tokens -> bf16 rows  ||  w1 fp32 transpose -> W1t --------
__global__ __launch_bounds__(256) void gather_trans1(
    const float* __restrict__ x, const int* __restrict__ pair_token,
    __hip_bfloat16* __restrict__ Xg,
    const float* __restrict__ w1, __hip_bfloat16* __restrict__ W1t)
{
  __shared__ __hip_bfloat16 tile[64][66];
  int bid = blockIdx.x;
  if (bid >= GATHB) {
    int i = bid - GATHB;                 // [0, 8192)
    int xq = i & 63, yq = (i >> 6) & 15, z = i >> 10;
    size_t mat = (size_t)DDIM * FDIM;
    trans64(w1 + (size_t)z * mat, W1t + (size_t)z * mat,
            DDIM, FDIM, xq * 64, yq * 64, threadIdx.x, tile);
    return;
  }
  int gid = bid * 256 + threadIdx.x;
  int r = gid >> 7;
  int c = (gid & 127) << 3;
  if (r >= PADMAX) return;
  int tk = pair_token[r];
  __hip_bfloat16 v[8];
  if (tk < 0) {
#pragma unroll
    for (int j = 0; j < 8; ++j) v[j] = __float2bfloat16(0.f);
  } else {
    const float* src = x + (size_t)tk * DDIM + c;
    f32x4 a = __builtin_nontemporal_load((const f32x4*)src);
    f32x4 b = __builtin_nontemporal_load((const f32x4*)(src + 4));
#pragma unroll
    for (int j = 0; j < 4; ++j) v[j] = __float2bfloat16(a[j]);
#pragma unroll
    for (int j = 0; j < 4; ++j) v[4 + j] = __float2bfloat16(b[j]);
  }
  *(us8*)(Xg + (size_t)r * DDIM + c) = *(const us8*)v;
}

// ------- 8-phase grouped GEMM, 256x256, BK=64, read-ahead pipeline, split-K -----
// PARTS: K split into PARTS slices; part p covers K in [p*LD/PARTS, ...), output
// goes to Out + p*pstride (bf16 partials, summed in combine). NT = LD/64/PARTS.
// FUSET: trailing blocks transpose w2 -> W2t (tail-fill).
template<int LD, int NT, int LDO, int NCOL, int PARTS, int SC, bool GELU, bool FUSET>
__global__ __launch_bounds__(512, 2) void moe_gemm8(
    const __hip_bfloat16* __restrict__ A, const __hip_bfloat16* __restrict__ B,
    __hip_bfloat16* __restrict__ Out,
    const int* __restrict__ tile_e, const int* __restrict__ tile_row,
    const int* __restrict__ numTiles,
    const float* __restrict__ w2, __hip_bfloat16* __restrict__ W2t,
    size_t pstride)
{
  __shared__ __align__(16) __hip_bfloat16 lds[8][8192];
  constexpr int NCP = NCOL * PARTS;
  if (FUSET && (int)blockIdx.x >= MAXT * NCP) {
    int i2 = ((int)blockIdx.x - MAXT * NCP) * 2 + (threadIdx.x >> 8);  // [0,8192)
    int xq = i2 & 15, yq = (i2 >> 4) & 63, z = i2 >> 10;
    int sub = threadIdx.x >> 8, tid = threadIdx.x & 255;
    __hip_bfloat16 (*tile)[66] =
        reinterpret_cast<__hip_bfloat16(*)[66]>(&lds[0][0] + sub * 64 * 66);
    size_t mat = (size_t)FDIM * DDIM;
    trans64(w2 + (size_t)z * mat, W2t + (size_t)z * mat,
            FDIM, DDIM, xq * 64, yq * 64, tid, tile);
    return;
  }
  constexpr int STU = 3 * SC;
  constexpr int NCG = NCP / SC;
  const int bid = blockIdx.x;
  const int xcd = bid & 7;
  const int idx = bid >> 3;
  const int stg = idx / STU;
  const int within = idx % STU;
  const int colg = stg % NCG;
  const int tg = stg / NCG;
  const int tl = tg * 3 + within % 3;
  const int colp = colg * SC + within / 3;   // [0, NCP)
  const int col = colp % NCOL;
  const int part = colp / NCOL;
  const int nT = *numTiles;
  const int tile = ((xcd * nT) >> 3) + tl;
  if (tile >= (((xcd + 1) * nT) >> 3)) return;

  const int t = threadIdx.x, lane = t & 63, w = t >> 6;
  const int wm = w >> 2, wn = w & 3;
  const int fr = lane & 15, fkg = lane >> 4;
  const size_t rowoff = (size_t)(w * 8 + (lane >> 3)) * LD + (((lane & 7) ^ (lane >> 3)) << 3);
  const int aoff = (wm * 64 + fr) * 64;
  const int boff = (wn * 32 + fr) * 64;
  const int swk0 = (fkg ^ (fr & 7)) * 8;
  const int swk1 = ((4 + fkg) ^ (fr & 7)) * 8;

  const int e = tile_e[tile];
  const int row0 = tile_row[tile];
  const int col0 = col * 256;
  const size_t koff = (size_t)part * (LD / PARTS);
  const __hip_bfloat16* Ab = A + (size_t)row0 * LD + koff;
  const __hip_bfloat16* Bb = B + (size_t)e * ((size_t)FDIM * DDIM) + (size_t)col0 * LD + koff;

  auto STAGEH = [&](const __hip_bfloat16* base, int mat, int half, int tt) {
    __hip_bfloat16* d = &lds[(((tt & 1) << 2) | (mat << 1) | half)][0] + w * 512;
    const __hip_bfloat16* s = base + (size_t)(half * 128) * LD + (size_t)tt * 64 + rowoff;
    GLOAD16(d, s);
    GLOAD16(d + 4096, s + (size_t)64 * LD);
  };

  f32x4 acc[4][4][2] = {};
  s16x8 af0[4][2], af1[4][2], b0[2][2], b1[2][2];

  STAGEH(Ab, 0, 0, 0); STAGEH(Bb, 1, 0, 0); STAGEH(Bb, 1, 1, 0); STAGEH(Ab, 0, 1, 0);
  STAGEH(Ab, 0, 0, 1);
  WAITVM(6);
  __builtin_amdgcn_s_barrier();
  MEMFENCE;
  {
    const __hip_bfloat16* A0r = &lds[0][0];
    const __hip_bfloat16* B0r = &lds[2][0];
#pragma unroll
    for (int m = 0; m < 4; ++m) {
      af0[m][0] = *(const s16x8*)(A0r + aoff + m * 1024 + swk0);
      af0[m][1] = *(const s16x8*)(A0r + aoff + m * 1024 + swk1);
    }
#pragma unroll
    for (int n = 0; n < 2; ++n) {
      b0[n][0] = *(const s16x8*)(B0r + boff + n * 1024 + swk0);
      b0[n][1] = *(const s16x8*)(B0r + boff + n * 1024 + swk1);
    }
  }

  for (int kt = 0; kt < NT; ++kt) {
    const int buf = kt & 1;
    const bool p1 = (kt + 1) < NT;
    const bool p2 = (kt + 2) < NT;
    const __hip_bfloat16* A1r = &lds[(buf << 2) | 1][0];
    const __hip_bfloat16* B1r = &lds[(buf << 2) | 3][0];
    const __hip_bfloat16* A0n = &lds[((buf ^ 1) << 2) | 0][0];
    const __hip_bfloat16* B0n = &lds[((buf ^ 1) << 2) | 2][0];

    // ---- ph2: read B1f(kt); MFMA q00 ----
    if (p1) STAGEH(Bb, 1, 0, kt + 1);
    if (p1) { WAITVM(6); } else { WAITVM(2); }
    __builtin_amdgcn_s_barrier();
    MEMFENCE;
#pragma unroll
    for (int n = 0; n < 2; ++n) {
      b1[n][0] = *(const s16x8*)(B1r + boff + n * 1024 + swk0);
      b1[n][1] = *(const s16x8*)(B1r + boff + n * 1024 + swk1);
    }
    __builtin_amdgcn_s_setprio(1);
#pragma unroll
    for (int kk = 0; kk < 2; ++kk)
#pragma unroll
      for (int m = 0; m < 4; ++m)
#pragma unroll
        for (int n = 0; n < 2; ++n)
          acc[0][m][n] = __builtin_amdgcn_mfma_f32_16x16x32_bf16(af0[m][kk], b0[n][kk], acc[0][m][n], 0, 0, 0);
    __builtin_amdgcn_s_setprio(0);
    MEMFENCE;

    // ---- ph3: read A1f(kt); MFMA q01 ----
    if (p1) STAGEH(Bb, 1, 1, kt + 1);
    if (p1) { WAITVM(6); } else { WAITVM(0); }
    __builtin_amdgcn_s_barrier();
    MEMFENCE;
#pragma unroll
    for (int m = 0; m < 4; ++m) {
      af1[m][0] = *(const s16x8*)(A1r + aoff + m * 1024 + swk0);
      af1[m][1] = *(const s16x8*)(A1r + aoff + m * 1024 + swk1);
    }
    __builtin_amdgcn_s_setprio(1);
#pragma unroll
    for (int kk = 0; kk < 2; ++kk)
#pragma unroll
      for (int m = 0; m < 4; ++m)
#pragma unroll
        for (int n = 0; n < 2; ++n)
          acc[1][m][n] = __builtin_amdgcn_mfma_f32_16x16x32_bf16(af0[m][kk], b1[n][kk], acc[1][m][n], 0, 0, 0);
    __builtin_amdgcn_s_setprio(0);
    MEMFENCE;

    // ---- ph4: MFMA q10 ----
    if (p1) STAGEH(Ab, 0, 1, kt + 1);
    __builtin_amdgcn_s_barrier();
    MEMFENCE;
    __builtin_amdgcn_s_setprio(1);
#pragma unroll
    for (int kk = 0; kk < 2; ++kk)
#pragma unroll
      for (int m = 0; m < 4; ++m)
#pragma unroll
        for (int n = 0; n < 2; ++n)
          acc[3][m][n] = __builtin_amdgcn_mfma_f32_16x16x32_bf16(af1[m][kk], b0[n][kk], acc[3][m][n], 0, 0, 0);
    __builtin_amdgcn_s_setprio(0);
    MEMFENCE;

    // ---- ph1(kt+1): read A0f,B0f(kt+1); MFMA q11(kt) ----
    if (p2) STAGEH(Ab, 0, 0, kt + 2);
    if (p1) { if (p2) { WAITVM(6); } else { WAITVM(4); } }
    __builtin_amdgcn_s_barrier();
    MEMFENCE;
    if (p1) {
#pragma unroll
      for (int m = 0; m < 4; ++m) {
        af0[m][0] = *(const s16x8*)(A0n + aoff + m * 1024 + swk0);
        af0[m][1] = *(const s16x8*)(A0n + aoff + m * 1024 + swk1);
      }
#pragma unroll
      for (int n = 0; n < 2; ++n) {
        b0[n][0] = *(const s16x8*)(B0n + boff + n * 1024 + swk0);
        b0[n][1] = *(const s16x8*)(B0n + boff + n * 1024 + swk1);
      }
    }
    __builtin_amdgcn_s_setprio(1);
#pragma unroll
    for (int kk = 0; kk < 2; ++kk)
#pragma unroll
      for (int m = 0; m < 4; ++m)
#pragma unroll
        for (int n = 0; n < 2; ++n)
          acc[2][m][n] = __builtin_amdgcn_mfma_f32_16x16x32_bf16(af1[m][kk], b1[n][kk], acc[2][m][n], 0, 0, 0);
    __builtin_amdgcn_s_setprio(0);
    MEMFENCE;
  }

  // ---- epilogue ----
  __hip_bfloat16* Ob = Out + (size_t)part * pstride;
  const int cbase = col0 + wn * 32 + fr;
#pragma unroll
  for (int mh = 0; mh < 2; ++mh) {
    const int qa = mh ? 3 : 0;
    const int qb = mh ? 2 : 1;
#pragma unroll
    for (int m = 0; m < 4; ++m) {
#pragma unroll
      for (int j = 0; j < 4; ++j) {
        int r = row0 + mh * 128 + wm * 64 + m * 16 + fkg * 4 + j;
        __hip_bfloat16* p = Ob + (size_t)r * LDO + cbase;
        float v0 = acc[qa][m][0][j];
        float v1 = acc[qa][m][1][j];
        float v2 = acc[qb][m][0][j];
        float v3 = acc[qb][m][1][j];
        if (GELU) {
          v0 = gelu_fast(v0); v1 = gelu_fast(v1);
          v2 = gelu_fast(v2); v3 = gelu_fast(v3);
        }
        p[0]   = __float2bfloat16(v0);
        p[16]  = __float2bfloat16(v1);
        p[128] = __float2bfloat16(v2);
        p[144] = __float2bfloat16(v3);
      }
    }
  }
}

// ------- combine: out[tok] = wa*sum_p E[p][sa] + wb*sum_p E[p][sb] -------
__global__ __launch_bounds__(256) void combine_kernel(
    const __hip_bfloat16* __restrict__ E, const int* __restrict__ tok_slot,
    const float* __restrict__ tok_w, float* __restrict__ out)
{
  const size_t PS = (size_t)PADMAX * DDIM;
  int tok = blockIdx.x;
  int sa = tok_slot[tok * 2], sb = tok_slot[tok * 2 + 1];
  float wa = tok_w[tok * 2], wb = tok_w[tok * 2 + 1];
  float* op = out + (size_t)tok * DDIM;
  int c = threadIdx.x * 4;
  float oa[4] = {0.f, 0.f, 0.f, 0.f}, ob[4] = {0.f, 0.f, 0.f, 0.f};
#pragma unroll
  for (int p = 0; p < 4; ++p) {
    us4 va = *(const us4*)(E + p * PS + (size_t)sa * DDIM + c);
    us4 vb = *(const us4*)(E + p * PS + (size_t)sb * DDIM + c);
#pragma unroll
    for (int j = 0; j < 4; ++j) { oa[j] += bf2f(va[j]); ob[j] += bf2f(vb[j]); }
  }
  float4 o;
  o.x = wa * oa[0] + wb * ob[0];
  o.y = wa * oa[1] + wb * ob[1];
  o.z = wa * oa[2] + wb * ob[2];
  o.w = wa * oa[3] + wb * ob[3];
  *(float4*)(op + c) = o;
}

extern "C" void kernel_launch(void* const* d_in, const int* in_sizes, int n_in,
                              void* d_out, int out_size, void* d_ws, size_t ws_size,
                              hipStream_t stream)
{
  const float* x      = (const float*)d_in[0];
  const float* gate_w = (const float*)d_in[1];
  const float* w1     = (const float*)d_in[2];
  const float* w2     = (const float*)d_in[3];
  float* out = (float*)d_out;

  char* ws = (char*)d_ws;
  size_t off = 0;
  auto alloc = [&](size_t bytes) -> void* {
    void* p = ws + off;
    off = (off + bytes + 255) & ~(size_t)255;
    return p;
  };
  int* ctrl = (int*)alloc(1024);
  int* counts     = ctrl + 0;
  int* fill       = ctrl + 8;
  int* padded_off = ctrl + 16;
  int* numTiles   = ctrl + 24;
  int*   tile_e     = (int*)alloc(MAXT * 4);
  int*   tile_row   = (int*)alloc(MAXT * 4);
  int*   tok_e      = (int*)alloc((size_t)T_TOK * 2 * 4);
  float* tok_w      = (float*)alloc((size_t)T_TOK * 2 * 4);
  int*   tok_slot   = (int*)alloc((size_t)T_TOK * 2 * 4);
  int*   pair_token = (int*)alloc((size_t)PADMAX * 4);
  // EoutAll: 4 K-part partial buffers; part 0 doubles as Xg (dead after ffn1)
  __hip_bfloat16* EoutAll = (__hip_bfloat16*)alloc((size_t)4 * PADMAX * DDIM * 2);
  __hip_bfloat16* Xg = EoutAll;
  __hip_bfloat16* W1t  = (__hip_bfloat16*)alloc((size_t)NEXP * FDIM * DDIM * 2);
  __hip_bfloat16* W2t  = (__hip_bfloat16*)alloc((size_t)NEXP * FDIM * DDIM * 2);
  __hip_bfloat16* Hbuf = (__hip_bfloat16*)alloc((size_t)PADMAX * FDIM * 2);
  (void)in_sizes; (void)n_in; (void)ws_size; (void)out_size;

  (void)hipMemsetAsync(d_ws, 0, 1024, stream);

  gate_kernel<<<T_TOK / 4, 256, 0, stream>>>(x, gate_w, tok_e, tok_w);
  count_kernel<<<T_TOK / 256, 256, 0, stream>>>(tok_e, counts);
  scan_kernel<<<1, 256, 0, stream>>>(counts, padded_off, tile_e, tile_row, numTiles,
                                     pair_token);
  scatter_kernel<<<T_TOK / 256, 256, 0, stream>>>(tok_e, padded_off, fill,
                                                  pair_token, tok_slot);
  // fused: token gather || w1 transpose
  gather_trans1<<<GATHB + TR1B, 256, 0, stream>>>(x, pair_token, Xg, w1, W1t);

  // ffn1 (K=1024, N=4096, PARTS=1) fused with w2 transpose (tail-fill)
  moe_gemm8<DDIM, DDIM / 64, FDIM, FDIM / 256, 1, 8, true, true>
      <<<MAXT * (FDIM / 256) + TR2B, 512, 0, stream>>>(Xg, W1t, Hbuf,
                                                       tile_e, tile_row, numTiles,
                                                       w2, W2t, 0);
  // ffn2 (K=4096 split 4x1024, N=1024): partials into EoutAll[0..3]
  moe_gemm8<FDIM, FDIM / 64 / 4, DDIM, DDIM / 256, 4, 4, false, false>
      <<<MAXT * (DDIM / 256) * 4, 512, 0, stream>>>(Hbuf, W2t, EoutAll,
                                                    tile_e, tile_row, numTiles,
                                                    nullptr, nullptr,
                                                    (size_t)PADMAX * DDIM);

  combine_kernel<<<T_TOK, 256, 0, stream>>>(EoutAll, tok_slot, tok_w, out);
}